// Round 8
// baseline (276.624 us; speedup 1.0000x reference)
//
#include <hip/hip_runtime.h>
#include <hip/hip_bf16.h>
#include <math.h>

#define EMBED_DIM 1024
#define NUM_HEADS 16
#define HEAD_DIM 64
#define BATCH 2
#define SEQ 2048

using short8  = __attribute__((ext_vector_type(8))) short;
using floatx4 = __attribute__((ext_vector_type(4))) float;

__device__ __forceinline__ ushort f2bf(float f) {
    unsigned u = __float_as_uint(f);
    u = (u + 0x7FFFu + ((u >> 16) & 1u)) >> 16;   // RNE
    return (ushort)u;
}

// pack two floats to bf16x2 (half-up rounding — P values are in [0,1], fine)
__device__ __forceinline__ unsigned bfpack2(float a, float b) {
    return ((__float_as_uint(a) + 0x8000u) >> 16) |
           (((__float_as_uint(b) + 0x8000u) >> 16) << 16);
}

// async global->LDS, 16B per lane; LDS dest = wave-uniform base + lane*16.
__device__ __forceinline__ void load_lds16(const ushort* g, ushort* l) {
    __builtin_amdgcn_global_load_lds(
        (const __attribute__((address_space(1))) void*)g,
        (__attribute__((address_space(3))) void*)l, 16, 0, 0);
}

// ---------------------------------------------------------------------------
// Fused prep: cast x -> bf16, transpose+cast W_qkv and W_out.
// ---------------------------------------------------------------------------
__device__ __forceinline__ void tc_tile(
    const float* __restrict__ W, ushort* __restrict__ Wt,
    int K, int N, int n0, int k0, float (*t)[65])
{
    const int c = threadIdx.x & 63, r0 = (threadIdx.x >> 6) * 16;
    #pragma unroll
    for (int r = 0; r < 16; ++r)
        t[r0 + r][c] = W[(size_t)(k0 + r0 + r) * N + n0 + c];
    __syncthreads();
    #pragma unroll
    for (int r = 0; r < 16; ++r)
        Wt[(size_t)(n0 + r0 + r) * K + k0 + c] = f2bf(t[c][r0 + r]);
}

__global__ __launch_bounds__(256) void prep_all(
    const float* __restrict__ x, const float* __restrict__ W_qkv,
    const float* __restrict__ W_out,
    ushort* __restrict__ xb, ushort* __restrict__ Wqb_t, ushort* __restrict__ Wob_t)
{
    __shared__ float t[64][65];
    const int bx = blockIdx.x;
    if (bx < 4096) {
        int i = (bx * 256 + threadIdx.x) * 4;
        float4 v = *(const float4*)&x[i];
        ushort4 o = { f2bf(v.x), f2bf(v.y), f2bf(v.z), f2bf(v.w) };
        *(ushort4*)&xb[i] = o;
    } else if (bx < 4096 + 768) {
        int b = bx - 4096;
        tc_tile(W_qkv, Wqb_t, 1024, 3072, (b % 48) * 64, (b / 48) * 64, t);
    } else {
        int b = bx - 4864;
        tc_tile(W_out, Wob_t, 1024, 1024, (b % 16) * 64, (b / 16) * 64, t);
    }
}

// ---------------------------------------------------------------------------
// bf16 MFMA GEMM core, 128x128, double-buffered — round-0 best (46.5us).
// Measured local optimum (rounds 1-6). Parked.
// ---------------------------------------------------------------------------
#define GK 1024

__device__ __forceinline__ void gemm_core(
    const ushort* __restrict__ A, const ushort* __restrict__ Bt,
    int m0, int n0, ushort* As0, ushort* As1, ushort* Bs0, ushort* Bs1,
    floatx4 acc[4][4])
{
    const int tid  = threadIdx.x;
    const int w    = tid >> 6;
    const int lane = tid & 63;
    const int col  = lane & 15;
    const int quad = lane >> 4;
    const int wm   = w >> 1, wn = w & 1;

    #pragma unroll
    for (int i = 0; i < 4; ++i)
        #pragma unroll
        for (int j = 0; j < 4; ++j)
            acc[i][j] = (floatx4){0.f, 0.f, 0.f, 0.f};

    const int o0   = w * 2048 + lane * 16;   // byte offset in 8KB tile
    const int row0 = o0 >> 6;
    const int ke0  = (o0 & 63) >> 1;
    const int loff = (w * 2048) >> 1;        // LDS element offset for this wave

    const ushort* ga = A  + (size_t)(m0 + row0) * GK + ke0;
    const ushort* gb = Bt + (size_t)(n0 + row0) * GK + ke0;

    // prologue: stage k=0 into buffer 0
    #pragma unroll
    for (int t = 0; t < 2; ++t) {
        load_lds16(ga + (size_t)t * 16 * GK, As0 + loff + t * 512);
        load_lds16(gb + (size_t)t * 16 * GK, Bs0 + loff + t * 512);
    }
    __syncthreads();

    for (int k0 = 0; k0 < GK; k0 += 32) {
        const int cur = (k0 >> 5) & 1;
        ushort* Ac = cur ? As1 : As0;
        ushort* Bc = cur ? Bs1 : Bs0;
        ushort* An = cur ? As0 : As1;
        ushort* Bn = cur ? Bs0 : Bs1;

        if (k0 + 32 < GK) {   // issue prefetch BEFORE compute
            #pragma unroll
            for (int t = 0; t < 2; ++t) {
                load_lds16(ga + (k0 + 32) + (size_t)t * 16 * GK, An + loff + t * 512);
                load_lds16(gb + (k0 + 32) + (size_t)t * 16 * GK, Bn + loff + t * 512);
            }
        }

        short8 af[4], bf[4];
        #pragma unroll
        for (int i = 0; i < 4; ++i)
            af[i] = *(const short8*)&Ac[(wm * 64 + i * 16 + col) * 32 + quad * 8];
        #pragma unroll
        for (int j = 0; j < 4; ++j)
            bf[j] = *(const short8*)&Bc[(wn * 64 + j * 16 + col) * 32 + quad * 8];
        #pragma unroll
        for (int i = 0; i < 4; ++i)
            #pragma unroll
            for (int j = 0; j < 4; ++j)
                acc[i][j] = __builtin_amdgcn_mfma_f32_16x16x32_bf16(af[i], bf[j], acc[i][j], 0, 0, 0);

        __syncthreads();
    }
}

// ---------------------------------------------------------------------------
// 128x64 core (gemm_out only: 512 blocks = 2 blocks/CU vs 1 at 128x128).
// ---------------------------------------------------------------------------
__device__ __forceinline__ void gemm_core64(
    const ushort* __restrict__ A, const ushort* __restrict__ Bt,
    int m0, int n0, ushort* As0, ushort* As1, ushort* Bs0, ushort* Bs1,
    floatx4 acc[4][2])
{
    const int tid  = threadIdx.x;
    const int w    = tid >> 6;
    const int lane = tid & 63;
    const int col  = lane & 15;
    const int quad = lane >> 4;
    const int wm   = w >> 1, wn = w & 1;

    #pragma unroll
    for (int i = 0; i < 4; ++i)
        #pragma unroll
        for (int j = 0; j < 2; ++j)
            acc[i][j] = (floatx4){0.f, 0.f, 0.f, 0.f};

    const int row0 = w * 16 + (lane >> 2);
    const int ke0  = ((lane & 3) ^ ((lane >> 3) & 3)) * 8;   // ushorts
    const int loff = w * 512;                                // ushort wave base

    const ushort* ga = A  + (size_t)(m0 + row0) * GK + ke0;
    const ushort* gb = Bt + (size_t)(n0 + row0) * GK + ke0;

    load_lds16(ga,               As0 + loff);
    load_lds16(ga + 64 * GK,     As0 + loff + 2048);
    load_lds16(gb,               Bs0 + loff);
    __syncthreads();

    const int sq = (quad ^ ((col >> 1) & 3)) * 8;

    for (int k0 = 0; k0 < GK; k0 += 32) {
        const int cur = (k0 >> 5) & 1;
        ushort* Ac = cur ? As1 : As0;
        ushort* Bc = cur ? Bs1 : Bs0;
        ushort* An = cur ? As0 : As1;
        ushort* Bn = cur ? Bs0 : Bs1;

        if (k0 + 32 < GK) {
            load_lds16(ga + (k0 + 32),           An + loff);
            load_lds16(ga + (k0 + 32) + 64 * GK, An + loff + 2048);
            load_lds16(gb + (k0 + 32),           Bn + loff);
        }

        short8 af[4], bf[2];
        #pragma unroll
        for (int i = 0; i < 4; ++i)
            af[i] = *(const short8*)&Ac[(wm * 64 + i * 16 + col) * 32 + sq];
        #pragma unroll
        for (int j = 0; j < 2; ++j)
            bf[j] = *(const short8*)&Bc[(wn * 32 + j * 16 + col) * 32 + sq];
        #pragma unroll
        for (int i = 0; i < 4; ++i)
            #pragma unroll
            for (int j = 0; j < 2; ++j)
                acc[i][j] = __builtin_amdgcn_mfma_f32_16x16x32_bf16(af[i], bf[j], acc[i][j], 0, 0, 0);

        __syncthreads();
    }
}

// GEMM1: qkv projection; fused split/cast; V emitted transposed. (128x128)
__global__ __launch_bounds__(256) void gemm_qkv_mfma(
    const ushort* __restrict__ A, const ushort* __restrict__ Bt,
    const float* __restrict__ bias,
    ushort* __restrict__ Qb, ushort* __restrict__ Kb, ushort* __restrict__ Vt)
{
    __shared__ __align__(16) ushort As[2][128 * 32];
    __shared__ __align__(16) ushort Bs[2][128 * 32];
    const int n0 = blockIdx.x * 128;
    const int m0 = blockIdx.y * 128;

    floatx4 acc[4][4];
    gemm_core(A, Bt, m0, n0, As[0], As[1], Bs[0], Bs[1], acc);

    const int lane = threadIdx.x & 63;
    const int w    = threadIdx.x >> 6;
    const int col  = lane & 15, quad = lane >> 4;
    const int wm   = w >> 1, wn = w & 1;

    #pragma unroll
    for (int j = 0; j < 4; ++j) {
        const int n = n0 + wn * 64 + j * 16 + col;
        const float bj = bias[n];
        const int part = n >> 10;
        const int h = (n >> 6) & 15;
        const int d = n & 63;
        #pragma unroll
        for (int i = 0; i < 4; ++i)
            #pragma unroll
            for (int r = 0; r < 4; ++r) {
                const int m = m0 + wm * 64 + i * 16 + quad * 4 + r;
                const int b = m >> 11, s = m & 2047;
                const int bh = b * 16 + h;
                const ushort bv = f2bf(acc[i][j][r] + bj);
                if (part == 0)      Qb[((size_t)bh * SEQ + s) * 64 + d] = bv;
                else if (part == 1) Kb[((size_t)bh * SEQ + s) * 64 + d] = bv;
                else                Vt[((size_t)bh * 64 + d) * SEQ + s] = bv;
            }
    }
}

// GEMM2: out = attn_b @ W_out + b_out -> fp32 (128x64 core, 2 blocks/CU)
__global__ __launch_bounds__(256) void gemm_out_mfma(
    const ushort* __restrict__ A, const ushort* __restrict__ Bt,
    const float* __restrict__ bias, float* __restrict__ out)
{
    __shared__ __align__(16) ushort As[2][128 * 32];
    __shared__ __align__(16) ushort Bs[2][64 * 32];
    const int n0 = blockIdx.x * 64;
    const int m0 = blockIdx.y * 128;

    floatx4 acc[4][2];
    gemm_core64(A, Bt, m0, n0, As[0], As[1], Bs[0], Bs[1], acc);

    const int lane = threadIdx.x & 63;
    const int w    = threadIdx.x >> 6;
    const int col  = lane & 15, quad = lane >> 4;
    const int wm   = w >> 1, wn = w & 1;

    #pragma unroll
    for (int j = 0; j < 2; ++j) {
        const int n = n0 + wn * 32 + j * 16 + col;
        const float bj = bias[n];
        #pragma unroll
        for (int i = 0; i < 4; ++i)
            #pragma unroll
            for (int r = 0; r < 4; ++r) {
                const int m = m0 + wm * 64 + i * 16 + quad * 4 + r;
                out[(size_t)m * EMBED_DIM + n] = acc[i][j][r] + bj;
            }
    }
}

// ---------------------------------------------------------------------------
// Flash attention v2 (round 7): NO K/V/Q LDS staging, NO barriers in the loop.
// K/V per bh = 8KB/tile, re-read by all 32 q-blocks of that bh; blocks with
// equal id%8 share bh (32 ≡ 0 mod 8) -> same XCD -> per-XCD working set
// 4 bh x 512KB = 2MB, L2-resident (Common-mistake #7 / m169: don't stage
// L2-fit data). Fragment addresses derived 1:1 from the old stage/read pair.
// Per key-tile per wave: 8 K-loads + 8 V-loads (16B/lane, issued before QK so
// latency hides under MFMA+softmax), 16 MFMA, wave-private P LDS roundtrip
// (intra-wave dep only -> compiler lgkmcnt, no barrier). LDS 49KB -> 9.4KB.
// ---------------------------------------------------------------------------
#define LP 72

__global__ __launch_bounds__(256) void attn_fused(
    const ushort* __restrict__ Qb, const ushort* __restrict__ Kb,
    const ushort* __restrict__ Vt, ushort* __restrict__ out)
{
    const int id = blockIdx.x;
    const int qt = 31 - (id >> 5);          // reversed: long blocks first (LPT)
    const int bh = id & 31;
    const int b  = bh >> 4, h = bh & 15;
    const int q0 = qt * 64;

    __shared__ __align__(16) ushort Ps[64 * LP];        // 9 KB (wave-private rows)
    __shared__ __align__(16) float  ls[4][16];

    const int tid  = threadIdx.x;
    const int w    = tid >> 6;
    const int lane = tid & 63;
    const int col  = lane & 15;
    const int quad = lane >> 4;

    // Q fragments direct from global (was: staged via LDS, same mapping)
    const ushort* Qg = Qb + ((size_t)bh * SEQ + q0 + w * 16 + col) * 64 + quad * 8;
    const short8 a0 = *(const short8*)&Qg[0];
    const short8 a1 = *(const short8*)&Qg[32];

    // per-lane K/V fragment bases (mapping verified vs old stage/read pair):
    //  K frag (kb,t,kt): Kb + bh*SEQ*64 + (kt*64 + kb*16 + col)*64 + t*32 + quad*8
    //  V frag (dbi,t,kt): Vt + (bh*64 + dbi*16 + col)*SEQ + kt*64 + t*32 + quad*8
    const ushort* Kg = Kb + (size_t)bh * SEQ * 64 + (size_t)col * 64 + quad * 8;
    const ushort* Vg = Vt + ((size_t)bh * 64 + col) * SEQ + quad * 8;

    floatx4 acc_o[4];
    #pragma unroll
    for (int dbi = 0; dbi < 4; ++dbi) acc_o[dbi] = (floatx4){0.f, 0.f, 0.f, 0.f};
    float l_lane = 0.f;
    const int myq = w * 16 + col;           // tile-local query owned in S^T

    for (int kt = 0; kt <= qt; ++kt) {
        const ushort* Kt_ = Kg + (size_t)kt * 64 * 64;
        const ushort* Vt_ = Vg + kt * 64;

        // K fragments (needed first)
        short8 kf[4][2];
        #pragma unroll
        for (int kb = 0; kb < 4; ++kb) {
            kf[kb][0] = *(const short8*)&Kt_[(size_t)(kb * 16) * 64];
            kf[kb][1] = *(const short8*)&Kt_[(size_t)(kb * 16) * 64 + 32];
        }
        // V fragments issued early — latency hides under QK^T + softmax
        short8 vb[4][2];
        #pragma unroll
        for (int dbi = 0; dbi < 4; ++dbi) {
            vb[dbi][0] = *(const short8*)&Vt_[(size_t)dbi * 16 * SEQ];
            vb[dbi][1] = *(const short8*)&Vt_[(size_t)dbi * 16 * SEQ + 32];
        }

        // ---- S^T = K Q^T ----
        floatx4 s_acc[4];
        #pragma unroll
        for (int kb = 0; kb < 4; ++kb) {
            floatx4 z = (floatx4){0.f, 0.f, 0.f, 0.f};
            z = __builtin_amdgcn_mfma_f32_16x16x32_bf16(kf[kb][0], a0, z, 0, 0, 0);
            z = __builtin_amdgcn_mfma_f32_16x16x32_bf16(kf[kb][1], a1, z, 0, 0, 0);
            s_acc[kb] = z;   // lane: query col; regs: keys kb*16+quad*4+r
        }

        // ---- p = exp(s/8); write P rows (wave-private) ----
        if (kt == qt) {
            #pragma unroll
            for (int kb = 0; kb < 4; ++kb) {
                const int kbase = kb * 16 + quad * 4;
                float p[4];
                #pragma unroll
                for (int r = 0; r < 4; ++r) {
                    float e = __expf(s_acc[kb][r] * 0.125f);
                    p[r] = (kbase + r > myq) ? 0.f : e;
                    l_lane += p[r];
                }
                uint2 u = { bfpack2(p[0], p[1]), bfpack2(p[2], p[3]) };
                *(uint2*)&Ps[myq * LP + kbase] = u;
            }
        } else {
            #pragma unroll
            for (int kb = 0; kb < 4; ++kb) {
                const int kbase = kb * 16 + quad * 4;
                float p[4];
                #pragma unroll
                for (int r = 0; r < 4; ++r) {
                    p[r] = __expf(s_acc[kb][r] * 0.125f);
                    l_lane += p[r];
                }
                uint2 u = { bfpack2(p[0], p[1]), bfpack2(p[2], p[3]) };
                *(uint2*)&Ps[myq * LP + kbase] = u;
            }
        }

        // ---- O += P V  (Ps rows wave-private; intra-wave lgkmcnt only) ----
        short8 pa0 = *(const short8*)&Ps[(w * 16 + col) * LP + quad * 8];
        short8 pa1 = *(const short8*)&Ps[(w * 16 + col) * LP + 32 + quad * 8];
        #pragma unroll
        for (int dbi = 0; dbi < 4; ++dbi) {
            acc_o[dbi] = __builtin_amdgcn_mfma_f32_16x16x32_bf16(pa0, vb[dbi][0], acc_o[dbi], 0, 0, 0);
            acc_o[dbi] = __builtin_amdgcn_mfma_f32_16x16x32_bf16(pa1, vb[dbi][1], acc_o[dbi], 0, 0, 0);
        }
    }

    // ---- finalize l ----
    l_lane += __shfl_xor(l_lane, 16);
    l_lane += __shfl_xor(l_lane, 32);
    if (quad == 0) ls[w][col] = 1.f / l_lane;   // wave-private
    float4 invv = *(const float4*)&ls[w][quad * 4];

    #pragma unroll
    for (int dbi = 0; dbi < 4; ++dbi)
        #pragma unroll
        for (int r = 0; r < 4; ++r) {
            int q = q0 + w * 16 + quad * 4 + r;
            int d = dbi * 16 + col;
            float inv = (r == 0) ? invv.x : (r == 1) ? invv.y : (r == 2) ? invv.z : invv.w;
            out[((size_t)(b * SEQ + q)) * EMBED_DIM + h * 64 + d] = f2bf(acc_o[dbi][r] * inv);
        }
}

// ---------------------------------------------------------------------------
extern "C" void kernel_launch(void* const* d_in, const int* in_sizes, int n_in,
                              void* d_out, int out_size, void* d_ws, size_t ws_size,
                              hipStream_t stream)
{
    const float* x     = (const float*)d_in[0];
    const float* W_qkv = (const float*)d_in[1];
    const float* b_qkv = (const float*)d_in[2];
    const float* W_out = (const float*)d_in[3];
    const float* b_out = (const float*)d_in[4];
    float* out = (float*)d_out;

    const int M  = BATCH * SEQ;            // 4096
    const int D  = EMBED_DIM;              // 1024
    const int N1 = 3 * D;                  // 3072
    const size_t HE = (size_t)BATCH * NUM_HEADS * SEQ * 64;  // 4M

    ushort* xb    = (ushort*)d_ws;
    ushort* Wqb_t = xb + (size_t)M * D;
    ushort* Wob_t = Wqb_t + (size_t)D * N1;
    ushort* Qb    = Wob_t + (size_t)D * D;
    ushort* Kb    = Qb + HE;
    ushort* Vt    = Kb + HE;
    ushort* attnb = Vt + HE;

    // 0) fused prep: cast x, transpose+cast weights
    prep_all<<<5120, 256, 0, stream>>>(x, W_qkv, W_out, xb, Wqb_t, Wob_t);

    // 1) qkv projection — 128x128 (round-0 best), 768 blocks = 3/CU
    gemm_qkv_mfma<<<dim3(N1 / 128, M / 128), 256, 0, stream>>>(
        xb, Wqb_t, b_qkv, Qb, Kb, Vt);

    // 2) flash attention — barrier-free, direct-from-L2 fragments
    attn_fused<<<dim3(32 * 32), 256, 0, stream>>>(Qb, Kb, Vt, attnb);

    // 3) output projection — 128x64, 512 blocks = 2/CU
    gemm_out_mfma<<<dim3(D / 64, M / 128), 256, 0, stream>>>(
        attnb, Wob_t, b_out, out);
}

// Round 9
// 196.973 us; speedup vs baseline: 1.4044x; 1.4044x over previous
//
#include <hip/hip_runtime.h>
#include <hip/hip_bf16.h>
#include <math.h>

#define EMBED_DIM 1024
#define NUM_HEADS 16
#define HEAD_DIM 64
#define BATCH 2
#define SEQ 2048

using short8  = __attribute__((ext_vector_type(8))) short;
using floatx4 = __attribute__((ext_vector_type(4))) float;

__device__ __forceinline__ ushort f2bf(float f) {
    unsigned u = __float_as_uint(f);
    u = (u + 0x7FFFu + ((u >> 16) & 1u)) >> 16;   // RNE
    return (ushort)u;
}

// pack two floats to bf16x2 (half-up rounding — P values are in [0,1], fine)
__device__ __forceinline__ unsigned bfpack2(float a, float b) {
    return ((__float_as_uint(a) + 0x8000u) >> 16) |
           (((__float_as_uint(b) + 0x8000u) >> 16) << 16);
}

// async global->LDS, 16B per lane; LDS dest = wave-uniform base + lane*16.
__device__ __forceinline__ void load_lds16(const ushort* g, ushort* l) {
    __builtin_amdgcn_global_load_lds(
        (const __attribute__((address_space(1))) void*)g,
        (__attribute__((address_space(3))) void*)l, 16, 0, 0);
}

// ---------------------------------------------------------------------------
// Fused prep: cast x -> bf16, transpose+cast W_qkv and W_out.
// ---------------------------------------------------------------------------
__device__ __forceinline__ void tc_tile(
    const float* __restrict__ W, ushort* __restrict__ Wt,
    int K, int N, int n0, int k0, float (*t)[65])
{
    const int c = threadIdx.x & 63, r0 = (threadIdx.x >> 6) * 16;
    #pragma unroll
    for (int r = 0; r < 16; ++r)
        t[r0 + r][c] = W[(size_t)(k0 + r0 + r) * N + n0 + c];
    __syncthreads();
    #pragma unroll
    for (int r = 0; r < 16; ++r)
        Wt[(size_t)(n0 + r0 + r) * K + k0 + c] = f2bf(t[c][r0 + r]);
}

__global__ __launch_bounds__(256) void prep_all(
    const float* __restrict__ x, const float* __restrict__ W_qkv,
    const float* __restrict__ W_out,
    ushort* __restrict__ xb, ushort* __restrict__ Wqb_t, ushort* __restrict__ Wob_t)
{
    __shared__ float t[64][65];
    const int bx = blockIdx.x;
    if (bx < 4096) {
        int i = (bx * 256 + threadIdx.x) * 4;
        float4 v = *(const float4*)&x[i];
        ushort4 o = { f2bf(v.x), f2bf(v.y), f2bf(v.z), f2bf(v.w) };
        *(ushort4*)&xb[i] = o;
    } else if (bx < 4096 + 768) {
        int b = bx - 4096;
        tc_tile(W_qkv, Wqb_t, 1024, 3072, (b % 48) * 64, (b / 48) * 64, t);
    } else {
        int b = bx - 4864;
        tc_tile(W_out, Wob_t, 1024, 1024, (b % 16) * 64, (b / 16) * 64, t);
    }
}

// ---------------------------------------------------------------------------
// bf16 MFMA GEMM core, 128x128, double-buffered — round-0 best (46.5us).
// Measured local optimum (rounds 1-6). Parked.
// ---------------------------------------------------------------------------
#define GK 1024

__device__ __forceinline__ void gemm_core(
    const ushort* __restrict__ A, const ushort* __restrict__ Bt,
    int m0, int n0, ushort* As0, ushort* As1, ushort* Bs0, ushort* Bs1,
    floatx4 acc[4][4])
{
    const int tid  = threadIdx.x;
    const int w    = tid >> 6;
    const int lane = tid & 63;
    const int col  = lane & 15;
    const int quad = lane >> 4;
    const int wm   = w >> 1, wn = w & 1;

    #pragma unroll
    for (int i = 0; i < 4; ++i)
        #pragma unroll
        for (int j = 0; j < 4; ++j)
            acc[i][j] = (floatx4){0.f, 0.f, 0.f, 0.f};

    const int o0   = w * 2048 + lane * 16;   // byte offset in 8KB tile
    const int row0 = o0 >> 6;
    const int ke0  = (o0 & 63) >> 1;
    const int loff = (w * 2048) >> 1;        // LDS element offset for this wave

    const ushort* ga = A  + (size_t)(m0 + row0) * GK + ke0;
    const ushort* gb = Bt + (size_t)(n0 + row0) * GK + ke0;

    // prologue: stage k=0 into buffer 0
    #pragma unroll
    for (int t = 0; t < 2; ++t) {
        load_lds16(ga + (size_t)t * 16 * GK, As0 + loff + t * 512);
        load_lds16(gb + (size_t)t * 16 * GK, Bs0 + loff + t * 512);
    }
    __syncthreads();

    for (int k0 = 0; k0 < GK; k0 += 32) {
        const int cur = (k0 >> 5) & 1;
        ushort* Ac = cur ? As1 : As0;
        ushort* Bc = cur ? Bs1 : Bs0;
        ushort* An = cur ? As0 : As1;
        ushort* Bn = cur ? Bs0 : Bs1;

        if (k0 + 32 < GK) {   // issue prefetch BEFORE compute
            #pragma unroll
            for (int t = 0; t < 2; ++t) {
                load_lds16(ga + (k0 + 32) + (size_t)t * 16 * GK, An + loff + t * 512);
                load_lds16(gb + (k0 + 32) + (size_t)t * 16 * GK, Bn + loff + t * 512);
            }
        }

        short8 af[4], bf[4];
        #pragma unroll
        for (int i = 0; i < 4; ++i)
            af[i] = *(const short8*)&Ac[(wm * 64 + i * 16 + col) * 32 + quad * 8];
        #pragma unroll
        for (int j = 0; j < 4; ++j)
            bf[j] = *(const short8*)&Bc[(wn * 64 + j * 16 + col) * 32 + quad * 8];
        #pragma unroll
        for (int i = 0; i < 4; ++i)
            #pragma unroll
            for (int j = 0; j < 4; ++j)
                acc[i][j] = __builtin_amdgcn_mfma_f32_16x16x32_bf16(af[i], bf[j], acc[i][j], 0, 0, 0);

        __syncthreads();
    }
}

// ---------------------------------------------------------------------------
// 128x64 core (gemm_out only: 512 blocks = 2 blocks/CU vs 1 at 128x128).
// ---------------------------------------------------------------------------
__device__ __forceinline__ void gemm_core64(
    const ushort* __restrict__ A, const ushort* __restrict__ Bt,
    int m0, int n0, ushort* As0, ushort* As1, ushort* Bs0, ushort* Bs1,
    floatx4 acc[4][2])
{
    const int tid  = threadIdx.x;
    const int w    = tid >> 6;
    const int lane = tid & 63;
    const int col  = lane & 15;
    const int quad = lane >> 4;
    const int wm   = w >> 1, wn = w & 1;

    #pragma unroll
    for (int i = 0; i < 4; ++i)
        #pragma unroll
        for (int j = 0; j < 2; ++j)
            acc[i][j] = (floatx4){0.f, 0.f, 0.f, 0.f};

    const int row0 = w * 16 + (lane >> 2);
    const int ke0  = ((lane & 3) ^ ((lane >> 3) & 3)) * 8;   // ushorts
    const int loff = w * 512;                                // ushort wave base

    const ushort* ga = A  + (size_t)(m0 + row0) * GK + ke0;
    const ushort* gb = Bt + (size_t)(n0 + row0) * GK + ke0;

    load_lds16(ga,               As0 + loff);
    load_lds16(ga + 64 * GK,     As0 + loff + 2048);
    load_lds16(gb,               Bs0 + loff);
    __syncthreads();

    const int sq = (quad ^ ((col >> 1) & 3)) * 8;

    for (int k0 = 0; k0 < GK; k0 += 32) {
        const int cur = (k0 >> 5) & 1;
        ushort* Ac = cur ? As1 : As0;
        ushort* Bc = cur ? Bs1 : Bs0;
        ushort* An = cur ? As0 : As1;
        ushort* Bn = cur ? Bs0 : Bs1;

        if (k0 + 32 < GK) {
            load_lds16(ga + (k0 + 32),           An + loff);
            load_lds16(ga + (k0 + 32) + 64 * GK, An + loff + 2048);
            load_lds16(gb + (k0 + 32),           Bn + loff);
        }

        short8 af[4], bf[2];
        #pragma unroll
        for (int i = 0; i < 4; ++i)
            af[i] = *(const short8*)&Ac[(wm * 64 + i * 16 + col) * 32 + sq];
        #pragma unroll
        for (int j = 0; j < 2; ++j)
            bf[j] = *(const short8*)&Bc[(wn * 32 + j * 16 + col) * 32 + sq];
        #pragma unroll
        for (int i = 0; i < 4; ++i)
            #pragma unroll
            for (int j = 0; j < 2; ++j)
                acc[i][j] = __builtin_amdgcn_mfma_f32_16x16x32_bf16(af[i], bf[j], acc[i][j], 0, 0, 0);

        __syncthreads();
    }
}

// GEMM1: qkv projection; fused split/cast; V emitted transposed. (128x128)
__global__ __launch_bounds__(256) void gemm_qkv_mfma(
    const ushort* __restrict__ A, const ushort* __restrict__ Bt,
    const float* __restrict__ bias,
    ushort* __restrict__ Qb, ushort* __restrict__ Kb, ushort* __restrict__ Vt)
{
    __shared__ __align__(16) ushort As[2][128 * 32];
    __shared__ __align__(16) ushort Bs[2][128 * 32];
    const int n0 = blockIdx.x * 128;
    const int m0 = blockIdx.y * 128;

    floatx4 acc[4][4];
    gemm_core(A, Bt, m0, n0, As[0], As[1], Bs[0], Bs[1], acc);

    const int lane = threadIdx.x & 63;
    const int w    = threadIdx.x >> 6;
    const int col  = lane & 15, quad = lane >> 4;
    const int wm   = w >> 1, wn = w & 1;

    #pragma unroll
    for (int j = 0; j < 4; ++j) {
        const int n = n0 + wn * 64 + j * 16 + col;
        const float bj = bias[n];
        const int part = n >> 10;
        const int h = (n >> 6) & 15;
        const int d = n & 63;
        #pragma unroll
        for (int i = 0; i < 4; ++i)
            #pragma unroll
            for (int r = 0; r < 4; ++r) {
                const int m = m0 + wm * 64 + i * 16 + quad * 4 + r;
                const int b = m >> 11, s = m & 2047;
                const int bh = b * 16 + h;
                const ushort bv = f2bf(acc[i][j][r] + bj);
                if (part == 0)      Qb[((size_t)bh * SEQ + s) * 64 + d] = bv;
                else if (part == 1) Kb[((size_t)bh * SEQ + s) * 64 + d] = bv;
                else                Vt[((size_t)bh * 64 + d) * SEQ + s] = bv;
            }
    }
}

// GEMM2: out = attn_b @ W_out + b_out -> fp32 (128x64 core, 2 blocks/CU)
__global__ __launch_bounds__(256) void gemm_out_mfma(
    const ushort* __restrict__ A, const ushort* __restrict__ Bt,
    const float* __restrict__ bias, float* __restrict__ out)
{
    __shared__ __align__(16) ushort As[2][128 * 32];
    __shared__ __align__(16) ushort Bs[2][64 * 32];
    const int n0 = blockIdx.x * 64;
    const int m0 = blockIdx.y * 128;

    floatx4 acc[4][2];
    gemm_core64(A, Bt, m0, n0, As[0], As[1], Bs[0], Bs[1], acc);

    const int lane = threadIdx.x & 63;
    const int w    = threadIdx.x >> 6;
    const int col  = lane & 15, quad = lane >> 4;
    const int wm   = w >> 1, wn = w & 1;

    #pragma unroll
    for (int j = 0; j < 2; ++j) {
        const int n = n0 + wn * 32 + j * 16 + col;
        const float bj = bias[n];
        #pragma unroll
        for (int i = 0; i < 4; ++i)
            #pragma unroll
            for (int r = 0; r < 4; ++r) {
                const int m = m0 + wm * 64 + i * 16 + quad * 4 + r;
                out[(size_t)m * EMBED_DIM + n] = acc[i][j][r] + bj;
            }
    }
}

// ---------------------------------------------------------------------------
// Flash attention v3 (round 9): staged K/V (r8 proved staging is the dedup:
// direct-from-L2 frags = 2.8x worse), but TWO q-tiles per block share each
// staged K/V tile. Pair (j, 31-j): tile-steps/bh 528 -> 392, and dual-active
// steps run 32 MFMA/wave per barrier (was 16). K/V LDS frags read ONCE per
// tile, reused by both q-tiles. Q read direct to regs (once per block).
// Grid 512 (2/CU, heavy j=0 first), LDS ~42KB.
// ---------------------------------------------------------------------------
#define LP 72

__global__ __launch_bounds__(256) void attn_fused(
    const ushort* __restrict__ Qb, const ushort* __restrict__ Kb,
    const ushort* __restrict__ Vt, ushort* __restrict__ out)
{
    const int id = blockIdx.x;
    const int j  = id >> 5;                 // 0..15, heaviest (32 steps) first
    const int bh = id & 31;
    const int b  = bh >> 4, h = bh & 15;
    const int qtA = j, qtB = 31 - j;        // qtA < qtB always
    const int q0A = qtA * 64, q0B = qtB * 64;

    __shared__ __align__(16) ushort Ks[2][8 * 512];     // 16 KB dbuf
    __shared__ __align__(16) ushort Vs[2][8 * 512];     // 16 KB dbuf
    __shared__ __align__(16) ushort Ps[64 * LP];        // 9 KB (wave-private rows)
    __shared__ __align__(16) float  lsA[4][16], lsB[4][16];

    const int tid  = threadIdx.x;
    const int w    = tid >> 6;
    const int lane = tid & 63;
    const int col  = lane & 15;
    const int quad = lane >> 4;

    // per-lane global staging pointers (fragment-order gather)
    const ushort* kg[2];
    const ushort* vg[2];
    #pragma unroll
    for (int t = 0; t < 2; ++t) {
        kg[t] = Kb + (size_t)bh * SEQ * 64 + (size_t)(w * 16 + col) * 64 + t * 32 + quad * 8;
        vg[t] = Vt + (size_t)bh * 64 * SEQ + (size_t)(w * 16 + col) * SEQ + t * 32 + quad * 8;
    }

    // Q fragments direct from global, once per block (16 rows x 64B gather)
    const ushort* QgA = Qb + ((size_t)bh * SEQ + q0A + w * 16 + col) * 64 + quad * 8;
    const ushort* QgB = Qb + ((size_t)bh * SEQ + q0B + w * 16 + col) * 64 + quad * 8;
    const short8 aA0 = *(const short8*)&QgA[0];
    const short8 aA1 = *(const short8*)&QgA[32];
    const short8 aB0 = *(const short8*)&QgB[0];
    const short8 aB1 = *(const short8*)&QgB[32];

    // prologue: stage K/V tile 0 into buffer 0
    #pragma unroll
    for (int t = 0; t < 2; ++t) {
        load_lds16(kg[t], &Ks[0][(w * 2 + t) * 512]);
        load_lds16(vg[t], &Vs[0][(w * 2 + t) * 512]);
        kg[t] += 64 * 64;   // -> tile 1
        vg[t] += 64;
    }
    __syncthreads();

    floatx4 accA[4], accB[4];
    #pragma unroll
    for (int dbi = 0; dbi < 4; ++dbi) {
        accA[dbi] = (floatx4){0.f, 0.f, 0.f, 0.f};
        accB[dbi] = (floatx4){0.f, 0.f, 0.f, 0.f};
    }
    float lA = 0.f, lB = 0.f;
    const int myq = w * 16 + col;           // tile-local query owned in S^T

    for (int kt = 0; kt <= qtB; ++kt) {
        const int cur = kt & 1;
        const ushort* Kc = Ks[cur];
        const ushort* Vc = Vs[cur];

        if (kt < qtB) {   // issue-early prefetch of next tile into other buffer
            ushort* Kn = (ushort*)Ks[cur ^ 1];
            ushort* Vn = (ushort*)Vs[cur ^ 1];
            #pragma unroll
            for (int t = 0; t < 2; ++t) {
                load_lds16(kg[t], &Kn[(w * 2 + t) * 512]);
                load_lds16(vg[t], &Vn[(w * 2 + t) * 512]);
                kg[t] += 64 * 64;
                vg[t] += 64;
            }
        }

        // K/V fragments: read ONCE, reused by both q-tiles
        short8 kf[4][2], vf[4][2];
        #pragma unroll
        for (int kb = 0; kb < 4; ++kb) {
            kf[kb][0] = *(const short8*)&Kc[(kb * 2 + 0) * 512 + lane * 8];
            kf[kb][1] = *(const short8*)&Kc[(kb * 2 + 1) * 512 + lane * 8];
        }
        #pragma unroll
        for (int dbi = 0; dbi < 4; ++dbi) {
            vf[dbi][0] = *(const short8*)&Vc[(dbi * 2 + 0) * 512 + lane * 8];
            vf[dbi][1] = *(const short8*)&Vc[(dbi * 2 + 1) * 512 + lane * 8];
        }

        // ---- tile A (active while kt <= qtA; block-uniform branch) ----
        if (kt <= qtA) {
            floatx4 s_acc[4];
            #pragma unroll
            for (int kb = 0; kb < 4; ++kb) {
                floatx4 z = (floatx4){0.f, 0.f, 0.f, 0.f};
                z = __builtin_amdgcn_mfma_f32_16x16x32_bf16(kf[kb][0], aA0, z, 0, 0, 0);
                z = __builtin_amdgcn_mfma_f32_16x16x32_bf16(kf[kb][1], aA1, z, 0, 0, 0);
                s_acc[kb] = z;
            }
            const bool diag = (kt == qtA);
            #pragma unroll
            for (int kb = 0; kb < 4; ++kb) {
                const int kbase = kb * 16 + quad * 4;
                float p[4];
                #pragma unroll
                for (int r = 0; r < 4; ++r) {
                    float e = __expf(s_acc[kb][r] * 0.125f);
                    p[r] = (diag && (kbase + r > myq)) ? 0.f : e;
                    lA += p[r];
                }
                uint2 u = { bfpack2(p[0], p[1]), bfpack2(p[2], p[3]) };
                *(uint2*)&Ps[myq * LP + kbase] = u;
            }
            short8 pa0 = *(const short8*)&Ps[myq * LP + quad * 8];
            short8 pa1 = *(const short8*)&Ps[myq * LP + 32 + quad * 8];
            #pragma unroll
            for (int dbi = 0; dbi < 4; ++dbi) {
                accA[dbi] = __builtin_amdgcn_mfma_f32_16x16x32_bf16(pa0, vf[dbi][0], accA[dbi], 0, 0, 0);
                accA[dbi] = __builtin_amdgcn_mfma_f32_16x16x32_bf16(pa1, vf[dbi][1], accA[dbi], 0, 0, 0);
            }
        }

        // ---- tile B (always active; Ps reuse ordered by lgkmcnt deps) ----
        {
            floatx4 s_acc[4];
            #pragma unroll
            for (int kb = 0; kb < 4; ++kb) {
                floatx4 z = (floatx4){0.f, 0.f, 0.f, 0.f};
                z = __builtin_amdgcn_mfma_f32_16x16x32_bf16(kf[kb][0], aB0, z, 0, 0, 0);
                z = __builtin_amdgcn_mfma_f32_16x16x32_bf16(kf[kb][1], aB1, z, 0, 0, 0);
                s_acc[kb] = z;
            }
            const bool diag = (kt == qtB);
            #pragma unroll
            for (int kb = 0; kb < 4; ++kb) {
                const int kbase = kb * 16 + quad * 4;
                float p[4];
                #pragma unroll
                for (int r = 0; r < 4; ++r) {
                    float e = __expf(s_acc[kb][r] * 0.125f);
                    p[r] = (diag && (kbase + r > myq)) ? 0.f : e;
                    lB += p[r];
                }
                uint2 u = { bfpack2(p[0], p[1]), bfpack2(p[2], p[3]) };
                *(uint2*)&Ps[myq * LP + kbase] = u;
            }
            short8 pa0 = *(const short8*)&Ps[myq * LP + quad * 8];
            short8 pa1 = *(const short8*)&Ps[myq * LP + 32 + quad * 8];
            #pragma unroll
            for (int dbi = 0; dbi < 4; ++dbi) {
                accB[dbi] = __builtin_amdgcn_mfma_f32_16x16x32_bf16(pa0, vf[dbi][0], accB[dbi], 0, 0, 0);
                accB[dbi] = __builtin_amdgcn_mfma_f32_16x16x32_bf16(pa1, vf[dbi][1], accB[dbi], 0, 0, 0);
            }
        }

        __syncthreads();   // prefetch landed (covered by compute above);
                           // fences cur-buffer overwrite two iters later
    }

    // ---- finalize l (wave-private; no barrier needed) ----
    lA += __shfl_xor(lA, 16); lA += __shfl_xor(lA, 32);
    lB += __shfl_xor(lB, 16); lB += __shfl_xor(lB, 32);
    if (quad == 0) { lsA[w][col] = 1.f / lA; lsB[w][col] = 1.f / lB; }
    float4 invA = *(const float4*)&lsA[w][quad * 4];
    float4 invB = *(const float4*)&lsB[w][quad * 4];

    #pragma unroll
    for (int dbi = 0; dbi < 4; ++dbi)
        #pragma unroll
        for (int r = 0; r < 4; ++r) {
            const int d = dbi * 16 + col;
            const int qa = q0A + w * 16 + quad * 4 + r;
            const int qb_ = q0B + w * 16 + quad * 4 + r;
            const float ia = (r == 0) ? invA.x : (r == 1) ? invA.y : (r == 2) ? invA.z : invA.w;
            const float ib = (r == 0) ? invB.x : (r == 1) ? invB.y : (r == 2) ? invB.z : invB.w;
            out[((size_t)(b * SEQ + qa)) * EMBED_DIM + h * 64 + d] = f2bf(accA[dbi][r] * ia);
            out[((size_t)(b * SEQ + qb_)) * EMBED_DIM + h * 64 + d] = f2bf(accB[dbi][r] * ib);
        }
}

// ---------------------------------------------------------------------------
extern "C" void kernel_launch(void* const* d_in, const int* in_sizes, int n_in,
                              void* d_out, int out_size, void* d_ws, size_t ws_size,
                              hipStream_t stream)
{
    const float* x     = (const float*)d_in[0];
    const float* W_qkv = (const float*)d_in[1];
    const float* b_qkv = (const float*)d_in[2];
    const float* W_out = (const float*)d_in[3];
    const float* b_out = (const float*)d_in[4];
    float* out = (float*)d_out;

    const int M  = BATCH * SEQ;            // 4096
    const int D  = EMBED_DIM;              // 1024
    const int N1 = 3 * D;                  // 3072
    const size_t HE = (size_t)BATCH * NUM_HEADS * SEQ * 64;  // 4M

    ushort* xb    = (ushort*)d_ws;
    ushort* Wqb_t = xb + (size_t)M * D;
    ushort* Wob_t = Wqb_t + (size_t)D * N1;
    ushort* Qb    = Wob_t + (size_t)D * D;
    ushort* Kb    = Qb + HE;
    ushort* Vt    = Kb + HE;
    ushort* attnb = Vt + HE;

    // 0) fused prep: cast x, transpose+cast weights
    prep_all<<<5120, 256, 0, stream>>>(x, W_qkv, W_out, xb, Wqb_t, Wob_t);

    // 1) qkv projection — 128x128 (round-0 best), 768 blocks = 3/CU
    gemm_qkv_mfma<<<dim3(N1 / 128, M / 128), 256, 0, stream>>>(
        xb, Wqb_t, b_qkv, Qb, Kb, Vt);

    // 2) flash attention — staged K/V, 2 q-tiles per block, 512 blocks
    attn_fused<<<dim3(512), 256, 0, stream>>>(Qb, Kb, Vt, attnb);

    // 3) output projection — 128x64, 512 blocks = 2/CU
    gemm_out_mfma<<<dim3(D / 64, M / 128), 256, 0, stream>>>(
        attnb, Wob_t, b_out, out);
}

// Round 10
// 195.490 us; speedup vs baseline: 1.4150x; 1.0076x over previous
//
#include <hip/hip_runtime.h>
#include <hip/hip_bf16.h>
#include <math.h>

#define EMBED_DIM 1024
#define NUM_HEADS 16
#define HEAD_DIM 64
#define BATCH 2
#define SEQ 2048

using short8  = __attribute__((ext_vector_type(8))) short;
using floatx4 = __attribute__((ext_vector_type(4))) float;

__device__ __forceinline__ ushort f2bf(float f) {
    unsigned u = __float_as_uint(f);
    u = (u + 0x7FFFu + ((u >> 16) & 1u)) >> 16;   // RNE
    return (ushort)u;
}

// pack two floats to bf16x2 (half-up rounding — P values are in [0,1], fine)
__device__ __forceinline__ unsigned bfpack2(float a, float b) {
    return ((__float_as_uint(a) + 0x8000u) >> 16) |
           (((__float_as_uint(b) + 0x8000u) >> 16) << 16);
}

// async global->LDS, 16B per lane; LDS dest = wave-uniform base + lane*16.
__device__ __forceinline__ void load_lds16(const ushort* g, ushort* l) {
    __builtin_amdgcn_global_load_lds(
        (const __attribute__((address_space(1))) void*)g,
        (__attribute__((address_space(3))) void*)l, 16, 0, 0);
}

// ---------------------------------------------------------------------------
// Fused prep: cast x -> bf16, transpose+cast W_qkv and W_out.
// ---------------------------------------------------------------------------
__device__ __forceinline__ void tc_tile(
    const float* __restrict__ W, ushort* __restrict__ Wt,
    int K, int N, int n0, int k0, float (*t)[65])
{
    const int c = threadIdx.x & 63, r0 = (threadIdx.x >> 6) * 16;
    #pragma unroll
    for (int r = 0; r < 16; ++r)
        t[r0 + r][c] = W[(size_t)(k0 + r0 + r) * N + n0 + c];
    __syncthreads();
    #pragma unroll
    for (int r = 0; r < 16; ++r)
        Wt[(size_t)(n0 + r0 + r) * K + k0 + c] = f2bf(t[c][r0 + r]);
}

__global__ __launch_bounds__(256) void prep_all(
    const float* __restrict__ x, const float* __restrict__ W_qkv,
    const float* __restrict__ W_out,
    ushort* __restrict__ xb, ushort* __restrict__ Wqb_t, ushort* __restrict__ Wob_t)
{
    __shared__ float t[64][65];
    const int bx = blockIdx.x;
    if (bx < 4096) {
        int i = (bx * 256 + threadIdx.x) * 4;
        float4 v = *(const float4*)&x[i];
        ushort4 o = { f2bf(v.x), f2bf(v.y), f2bf(v.z), f2bf(v.w) };
        *(ushort4*)&xb[i] = o;
    } else if (bx < 4096 + 768) {
        int b = bx - 4096;
        tc_tile(W_qkv, Wqb_t, 1024, 3072, (b % 48) * 64, (b / 48) * 64, t);
    } else {
        int b = bx - 4864;
        tc_tile(W_out, Wob_t, 1024, 1024, (b % 16) * 64, (b / 16) * 64, t);
    }
}

// ---------------------------------------------------------------------------
// bf16 MFMA GEMM core, 128x128, double-buffered — round-0 best (46.5us).
// Measured local optimum (rounds 1-6). Parked.
// ---------------------------------------------------------------------------
#define GK 1024

__device__ __forceinline__ void gemm_core(
    const ushort* __restrict__ A, const ushort* __restrict__ Bt,
    int m0, int n0, ushort* As0, ushort* As1, ushort* Bs0, ushort* Bs1,
    floatx4 acc[4][4])
{
    const int tid  = threadIdx.x;
    const int w    = tid >> 6;
    const int lane = tid & 63;
    const int col  = lane & 15;
    const int quad = lane >> 4;
    const int wm   = w >> 1, wn = w & 1;

    #pragma unroll
    for (int i = 0; i < 4; ++i)
        #pragma unroll
        for (int j = 0; j < 4; ++j)
            acc[i][j] = (floatx4){0.f, 0.f, 0.f, 0.f};

    const int o0   = w * 2048 + lane * 16;   // byte offset in 8KB tile
    const int row0 = o0 >> 6;
    const int ke0  = (o0 & 63) >> 1;
    const int loff = (w * 2048) >> 1;        // LDS element offset for this wave

    const ushort* ga = A  + (size_t)(m0 + row0) * GK + ke0;
    const ushort* gb = Bt + (size_t)(n0 + row0) * GK + ke0;

    // prologue: stage k=0 into buffer 0
    #pragma unroll
    for (int t = 0; t < 2; ++t) {
        load_lds16(ga + (size_t)t * 16 * GK, As0 + loff + t * 512);
        load_lds16(gb + (size_t)t * 16 * GK, Bs0 + loff + t * 512);
    }
    __syncthreads();

    for (int k0 = 0; k0 < GK; k0 += 32) {
        const int cur = (k0 >> 5) & 1;
        ushort* Ac = cur ? As1 : As0;
        ushort* Bc = cur ? Bs1 : Bs0;
        ushort* An = cur ? As0 : As1;
        ushort* Bn = cur ? Bs0 : Bs1;

        if (k0 + 32 < GK) {   // issue prefetch BEFORE compute
            #pragma unroll
            for (int t = 0; t < 2; ++t) {
                load_lds16(ga + (k0 + 32) + (size_t)t * 16 * GK, An + loff + t * 512);
                load_lds16(gb + (k0 + 32) + (size_t)t * 16 * GK, Bn + loff + t * 512);
            }
        }

        short8 af[4], bf[4];
        #pragma unroll
        for (int i = 0; i < 4; ++i)
            af[i] = *(const short8*)&Ac[(wm * 64 + i * 16 + col) * 32 + quad * 8];
        #pragma unroll
        for (int j = 0; j < 4; ++j)
            bf[j] = *(const short8*)&Bc[(wn * 64 + j * 16 + col) * 32 + quad * 8];
        #pragma unroll
        for (int i = 0; i < 4; ++i)
            #pragma unroll
            for (int j = 0; j < 4; ++j)
                acc[i][j] = __builtin_amdgcn_mfma_f32_16x16x32_bf16(af[i], bf[j], acc[i][j], 0, 0, 0);

        __syncthreads();
    }
}

// ---------------------------------------------------------------------------
// 128x64 core (gemm_out only: 512 blocks = 2 blocks/CU vs 1 at 128x128).
// ---------------------------------------------------------------------------
__device__ __forceinline__ void gemm_core64(
    const ushort* __restrict__ A, const ushort* __restrict__ Bt,
    int m0, int n0, ushort* As0, ushort* As1, ushort* Bs0, ushort* Bs1,
    floatx4 acc[4][2])
{
    const int tid  = threadIdx.x;
    const int w    = tid >> 6;
    const int lane = tid & 63;
    const int col  = lane & 15;
    const int quad = lane >> 4;
    const int wm   = w >> 1, wn = w & 1;

    #pragma unroll
    for (int i = 0; i < 4; ++i)
        #pragma unroll
        for (int j = 0; j < 2; ++j)
            acc[i][j] = (floatx4){0.f, 0.f, 0.f, 0.f};

    const int row0 = w * 16 + (lane >> 2);
    const int ke0  = ((lane & 3) ^ ((lane >> 3) & 3)) * 8;   // ushorts
    const int loff = w * 512;                                // ushort wave base

    const ushort* ga = A  + (size_t)(m0 + row0) * GK + ke0;
    const ushort* gb = Bt + (size_t)(n0 + row0) * GK + ke0;

    load_lds16(ga,               As0 + loff);
    load_lds16(ga + 64 * GK,     As0 + loff + 2048);
    load_lds16(gb,               Bs0 + loff);
    __syncthreads();

    const int sq = (quad ^ ((col >> 1) & 3)) * 8;

    for (int k0 = 0; k0 < GK; k0 += 32) {
        const int cur = (k0 >> 5) & 1;
        ushort* Ac = cur ? As1 : As0;
        ushort* Bc = cur ? Bs1 : Bs0;
        ushort* An = cur ? As0 : As1;
        ushort* Bn = cur ? Bs0 : Bs1;

        if (k0 + 32 < GK) {
            load_lds16(ga + (k0 + 32),           An + loff);
            load_lds16(ga + (k0 + 32) + 64 * GK, An + loff + 2048);
            load_lds16(gb + (k0 + 32),           Bn + loff);
        }

        short8 af[4], bf[2];
        #pragma unroll
        for (int i = 0; i < 4; ++i)
            af[i] = *(const short8*)&Ac[(wm * 64 + i * 16 + col) * 32 + sq];
        #pragma unroll
        for (int j = 0; j < 2; ++j)
            bf[j] = *(const short8*)&Bc[(wn * 32 + j * 16 + col) * 32 + sq];
        #pragma unroll
        for (int i = 0; i < 4; ++i)
            #pragma unroll
            for (int j = 0; j < 2; ++j)
                acc[i][j] = __builtin_amdgcn_mfma_f32_16x16x32_bf16(af[i], bf[j], acc[i][j], 0, 0, 0);

        __syncthreads();
    }
}

// GEMM1: qkv projection; fused split/cast; V emitted transposed. (128x128)
__global__ __launch_bounds__(256) void gemm_qkv_mfma(
    const ushort* __restrict__ A, const ushort* __restrict__ Bt,
    const float* __restrict__ bias,
    ushort* __restrict__ Qb, ushort* __restrict__ Kb, ushort* __restrict__ Vt)
{
    __shared__ __align__(16) ushort As[2][128 * 32];
    __shared__ __align__(16) ushort Bs[2][128 * 32];
    const int n0 = blockIdx.x * 128;
    const int m0 = blockIdx.y * 128;

    floatx4 acc[4][4];
    gemm_core(A, Bt, m0, n0, As[0], As[1], Bs[0], Bs[1], acc);

    const int lane = threadIdx.x & 63;
    const int w    = threadIdx.x >> 6;
    const int col  = lane & 15, quad = lane >> 4;
    const int wm   = w >> 1, wn = w & 1;

    #pragma unroll
    for (int j = 0; j < 4; ++j) {
        const int n = n0 + wn * 64 + j * 16 + col;
        const float bj = bias[n];
        const int part = n >> 10;
        const int h = (n >> 6) & 15;
        const int d = n & 63;
        #pragma unroll
        for (int i = 0; i < 4; ++i)
            #pragma unroll
            for (int r = 0; r < 4; ++r) {
                const int m = m0 + wm * 64 + i * 16 + quad * 4 + r;
                const int b = m >> 11, s = m & 2047;
                const int bh = b * 16 + h;
                const ushort bv = f2bf(acc[i][j][r] + bj);
                if (part == 0)      Qb[((size_t)bh * SEQ + s) * 64 + d] = bv;
                else if (part == 1) Kb[((size_t)bh * SEQ + s) * 64 + d] = bv;
                else                Vt[((size_t)bh * 64 + d) * SEQ + s] = bv;
            }
    }
}

// GEMM2: out = attn_b @ W_out + b_out -> fp32 (128x64 core, 2 blocks/CU)
__global__ __launch_bounds__(256) void gemm_out_mfma(
    const ushort* __restrict__ A, const ushort* __restrict__ Bt,
    const float* __restrict__ bias, float* __restrict__ out)
{
    __shared__ __align__(16) ushort As[2][128 * 32];
    __shared__ __align__(16) ushort Bs[2][64 * 32];
    const int n0 = blockIdx.x * 64;
    const int m0 = blockIdx.y * 128;

    floatx4 acc[4][2];
    gemm_core64(A, Bt, m0, n0, As[0], As[1], Bs[0], Bs[1], acc);

    const int lane = threadIdx.x & 63;
    const int w    = threadIdx.x >> 6;
    const int col  = lane & 15, quad = lane >> 4;
    const int wm   = w >> 1, wn = w & 1;

    #pragma unroll
    for (int j = 0; j < 2; ++j) {
        const int n = n0 + wn * 32 + j * 16 + col;
        const float bj = bias[n];
        #pragma unroll
        for (int i = 0; i < 4; ++i)
            #pragma unroll
            for (int r = 0; r < 4; ++r) {
                const int m = m0 + wm * 64 + i * 16 + quad * 4 + r;
                out[(size_t)m * EMBED_DIM + n] = acc[i][j][r] + bj;
            }
    }
}

// ---------------------------------------------------------------------------
// Flash attention v4 (round 10): r7's staged v1 structure (best measured,
// ~48us) with two local tweaks:
//   (a) Q read direct to registers (validated mapping from r8/r9) — drops the
//       8KB Qs buffer and its staging/reads; LDS 49.4 -> 41.4KB (still 3/CU,
//       grid 1024 = 4/CU capped at 3 by LDS).
//   (b) s_setprio(1/0) around the QK^T and PV MFMA clusters (T5: +4-7% attn,
//       m191 — waves desync across the softmax VALU phase, so priority
//       arbitration has something to do; GEMM-lockstep null doesn't apply).
// ---------------------------------------------------------------------------
#define LP 72

__global__ __launch_bounds__(256) void attn_fused(
    const ushort* __restrict__ Qb, const ushort* __restrict__ Kb,
    const ushort* __restrict__ Vt, ushort* __restrict__ out)
{
    const int id = blockIdx.x;
    const int qt = 31 - (id >> 5);          // reversed: long blocks first (LPT)
    const int bh = id & 31;
    const int b  = bh >> 4, h = bh & 15;
    const int q0 = qt * 64;

    __shared__ __align__(16) ushort Ks[2][8 * 512];     // 16 KB dbuf
    __shared__ __align__(16) ushort Vs[2][8 * 512];     // 16 KB dbuf
    __shared__ __align__(16) ushort Ps[64 * LP];        // 9 KB
    __shared__ __align__(16) float  ls[4][16];

    const int tid  = threadIdx.x;
    const int w    = tid >> 6;
    const int lane = tid & 63;
    const int col  = lane & 15;
    const int quad = lane >> 4;

    // per-lane global staging pointers (fragment-order gather)
    const ushort* kg[2];
    const ushort* vg[2];
    #pragma unroll
    for (int t = 0; t < 2; ++t) {
        kg[t] = Kb + (size_t)bh * SEQ * 64 + (size_t)(w * 16 + col) * 64 + t * 32 + quad * 8;
        vg[t] = Vt + (size_t)bh * 64 * SEQ + (size_t)(w * 16 + col) * SEQ + t * 32 + quad * 8;
    }

    // Q fragments direct from global, once per block (mapping validated r8/r9)
    const ushort* Qg = Qb + ((size_t)bh * SEQ + q0 + w * 16 + col) * 64 + quad * 8;
    const short8 a0 = *(const short8*)&Qg[0];
    const short8 a1 = *(const short8*)&Qg[32];

    // prologue: stage K/V tile 0 into buffer 0
    #pragma unroll
    for (int t = 0; t < 2; ++t) {
        load_lds16(kg[t], &Ks[0][(w * 2 + t) * 512]);
        load_lds16(vg[t], &Vs[0][(w * 2 + t) * 512]);
        kg[t] += 64 * 64;   // -> tile 1
        vg[t] += 64;
    }
    __syncthreads();

    floatx4 acc_o[4];
    #pragma unroll
    for (int dbi = 0; dbi < 4; ++dbi) acc_o[dbi] = (floatx4){0.f, 0.f, 0.f, 0.f};
    float l_lane = 0.f;
    const int myq = w * 16 + col;           // tile-local query owned in S^T

    for (int kt = 0; kt <= qt; ++kt) {
        const int cur = kt & 1;
        const ushort* Kc = Ks[cur];
        const ushort* Vc = Vs[cur];

        if (kt < qt) {   // issue-early prefetch of next tile into other buffer
            ushort* Kn = (ushort*)Ks[cur ^ 1];
            ushort* Vn = (ushort*)Vs[cur ^ 1];
            #pragma unroll
            for (int t = 0; t < 2; ++t) {
                load_lds16(kg[t], &Kn[(w * 2 + t) * 512]);
                load_lds16(vg[t], &Vn[(w * 2 + t) * 512]);
                kg[t] += 64 * 64;
                vg[t] += 64;
            }
        }

        // ---- S^T = K Q^T ----
        floatx4 s_acc[4];
        __builtin_amdgcn_s_setprio(1);
        #pragma unroll
        for (int kb = 0; kb < 4; ++kb) {
            short8 k0f = *(const short8*)&Kc[(kb * 2 + 0) * 512 + lane * 8];
            short8 k1f = *(const short8*)&Kc[(kb * 2 + 1) * 512 + lane * 8];
            floatx4 z = (floatx4){0.f, 0.f, 0.f, 0.f};
            z = __builtin_amdgcn_mfma_f32_16x16x32_bf16(k0f, a0, z, 0, 0, 0);
            z = __builtin_amdgcn_mfma_f32_16x16x32_bf16(k1f, a1, z, 0, 0, 0);
            s_acc[kb] = z;   // lane: query col; regs: keys kb*16+quad*4+r
        }
        __builtin_amdgcn_s_setprio(0);

        // ---- p = exp(s/8); write P rows ----
        if (kt == qt) {
            #pragma unroll
            for (int kb = 0; kb < 4; ++kb) {
                const int kbase = kb * 16 + quad * 4;
                float p[4];
                #pragma unroll
                for (int r = 0; r < 4; ++r) {
                    float e = __expf(s_acc[kb][r] * 0.125f);
                    p[r] = (kbase + r > myq) ? 0.f : e;
                    l_lane += p[r];
                }
                uint2 u = { bfpack2(p[0], p[1]), bfpack2(p[2], p[3]) };
                *(uint2*)&Ps[myq * LP + kbase] = u;
            }
        } else {
            #pragma unroll
            for (int kb = 0; kb < 4; ++kb) {
                const int kbase = kb * 16 + quad * 4;
                float p[4];
                #pragma unroll
                for (int r = 0; r < 4; ++r) {
                    p[r] = __expf(s_acc[kb][r] * 0.125f);
                    l_lane += p[r];
                }
                uint2 u = { bfpack2(p[0], p[1]), bfpack2(p[2], p[3]) };
                *(uint2*)&Ps[myq * LP + kbase] = u;
            }
        }

        // ---- O += P V  (Ps rows wave-private) ----
        short8 pa0 = *(const short8*)&Ps[(w * 16 + col) * LP + quad * 8];
        short8 pa1 = *(const short8*)&Ps[(w * 16 + col) * LP + 32 + quad * 8];
        __builtin_amdgcn_s_setprio(1);
        #pragma unroll
        for (int dbi = 0; dbi < 4; ++dbi) {
            short8 vb0 = *(const short8*)&Vc[(dbi * 2 + 0) * 512 + lane * 8];
            short8 vb1 = *(const short8*)&Vc[(dbi * 2 + 1) * 512 + lane * 8];
            acc_o[dbi] = __builtin_amdgcn_mfma_f32_16x16x32_bf16(pa0, vb0, acc_o[dbi], 0, 0, 0);
            acc_o[dbi] = __builtin_amdgcn_mfma_f32_16x16x32_bf16(pa1, vb1, acc_o[dbi], 0, 0, 0);
        }
        __builtin_amdgcn_s_setprio(0);

        __syncthreads();   // prefetch landed (covered by compute above);
                           // fences cur-buffer overwrite two iters later
    }

    // ---- finalize l ----
    l_lane += __shfl_xor(l_lane, 16);
    l_lane += __shfl_xor(l_lane, 32);
    if (quad == 0) ls[w][col] = 1.f / l_lane;   // wave-private
    float4 invv = *(const float4*)&ls[w][quad * 4];

    #pragma unroll
    for (int dbi = 0; dbi < 4; ++dbi)
        #pragma unroll
        for (int r = 0; r < 4; ++r) {
            int q = q0 + w * 16 + quad * 4 + r;
            int d = dbi * 16 + col;
            float inv = (r == 0) ? invv.x : (r == 1) ? invv.y : (r == 2) ? invv.z : invv.w;
            out[((size_t)(b * SEQ + q)) * EMBED_DIM + h * 64 + d] = f2bf(acc_o[dbi][r] * inv);
        }
}

// ---------------------------------------------------------------------------
extern "C" void kernel_launch(void* const* d_in, const int* in_sizes, int n_in,
                              void* d_out, int out_size, void* d_ws, size_t ws_size,
                              hipStream_t stream)
{
    const float* x     = (const float*)d_in[0];
    const float* W_qkv = (const float*)d_in[1];
    const float* b_qkv = (const float*)d_in[2];
    const float* W_out = (const float*)d_in[3];
    const float* b_out = (const float*)d_in[4];
    float* out = (float*)d_out;

    const int M  = BATCH * SEQ;            // 4096
    const int D  = EMBED_DIM;              // 1024
    const int N1 = 3 * D;                  // 3072
    const size_t HE = (size_t)BATCH * NUM_HEADS * SEQ * 64;  // 4M

    ushort* xb    = (ushort*)d_ws;
    ushort* Wqb_t = xb + (size_t)M * D;
    ushort* Wob_t = Wqb_t + (size_t)D * N1;
    ushort* Qb    = Wob_t + (size_t)D * D;
    ushort* Kb    = Qb + HE;
    ushort* Vt    = Kb + HE;
    ushort* attnb = Vt + HE;

    // 0) fused prep: cast x, transpose+cast weights
    prep_all<<<5120, 256, 0, stream>>>(x, W_qkv, W_out, xb, Wqb_t, Wob_t);

    // 1) qkv projection — 128x128 (round-0 best), 768 blocks = 3/CU
    gemm_qkv_mfma<<<dim3(N1 / 128, M / 128), 256, 0, stream>>>(
        xb, Wqb_t, b_qkv, Qb, Kb, Vt);

    // 2) flash attention — staged v1 + Q-direct + setprio, 1024 blocks
    attn_fused<<<dim3(32 * 32), 256, 0, stream>>>(Qb, Kb, Vt, attnb);

    // 3) output projection — 128x64, 512 blocks = 2/CU
    gemm_out_mfma<<<dim3(D / 64, M / 128), 256, 0, stream>>>(
        attnb, Wob_t, b_out, out);
}

// Round 11
// 188.710 us; speedup vs baseline: 1.4659x; 1.0359x over previous
//
#include <hip/hip_runtime.h>
#include <hip/hip_bf16.h>
#include <math.h>

#define EMBED_DIM 1024
#define NUM_HEADS 16
#define HEAD_DIM 64
#define BATCH 2
#define SEQ 2048

using short8  = __attribute__((ext_vector_type(8))) short;
using floatx4 = __attribute__((ext_vector_type(4))) float;

__device__ __forceinline__ ushort f2bf(float f) {
    unsigned u = __float_as_uint(f);
    u = (u + 0x7FFFu + ((u >> 16) & 1u)) >> 16;   // RNE
    return (ushort)u;
}

// pack two floats to bf16x2 (half-up rounding — P values are in [0,1], fine)
__device__ __forceinline__ unsigned bfpack2(float a, float b) {
    return ((__float_as_uint(a) + 0x8000u) >> 16) |
           (((__float_as_uint(b) + 0x8000u) >> 16) << 16);
}

// async global->LDS, 16B per lane; LDS dest = wave-uniform base + lane*16.
__device__ __forceinline__ void load_lds16(const ushort* g, ushort* l) {
    __builtin_amdgcn_global_load_lds(
        (const __attribute__((address_space(1))) void*)g,
        (__attribute__((address_space(3))) void*)l, 16, 0, 0);
}

// ---------------------------------------------------------------------------
// Fused prep: cast x -> bf16, transpose+cast W_qkv and W_out.
// ---------------------------------------------------------------------------
__device__ __forceinline__ void tc_tile(
    const float* __restrict__ W, ushort* __restrict__ Wt,
    int K, int N, int n0, int k0, float (*t)[65])
{
    const int c = threadIdx.x & 63, r0 = (threadIdx.x >> 6) * 16;
    #pragma unroll
    for (int r = 0; r < 16; ++r)
        t[r0 + r][c] = W[(size_t)(k0 + r0 + r) * N + n0 + c];
    __syncthreads();
    #pragma unroll
    for (int r = 0; r < 16; ++r)
        Wt[(size_t)(n0 + r0 + r) * K + k0 + c] = f2bf(t[c][r0 + r]);
}

__global__ __launch_bounds__(256) void prep_all(
    const float* __restrict__ x, const float* __restrict__ W_qkv,
    const float* __restrict__ W_out,
    ushort* __restrict__ xb, ushort* __restrict__ Wqb_t, ushort* __restrict__ Wob_t)
{
    __shared__ float t[64][65];
    const int bx = blockIdx.x;
    if (bx < 4096) {
        int i = (bx * 256 + threadIdx.x) * 4;
        float4 v = *(const float4*)&x[i];
        ushort4 o = { f2bf(v.x), f2bf(v.y), f2bf(v.z), f2bf(v.w) };
        *(ushort4*)&xb[i] = o;
    } else if (bx < 4096 + 768) {
        int b = bx - 4096;
        tc_tile(W_qkv, Wqb_t, 1024, 3072, (b % 48) * 64, (b / 48) * 64, t);
    } else {
        int b = bx - 4864;
        tc_tile(W_out, Wob_t, 1024, 1024, (b % 16) * 64, (b / 16) * 64, t);
    }
}

// ---------------------------------------------------------------------------
// bf16 MFMA GEMM core, 128x128, double-buffered — round-0 best (46.5us).
// Measured local optimum (rounds 1-6): swizzle/schedule/tile/occupancy
// perturbations all null or negative. Parked.
// ---------------------------------------------------------------------------
#define GK 1024

__device__ __forceinline__ void gemm_core(
    const ushort* __restrict__ A, const ushort* __restrict__ Bt,
    int m0, int n0, ushort* As0, ushort* As1, ushort* Bs0, ushort* Bs1,
    floatx4 acc[4][4])
{
    const int tid  = threadIdx.x;
    const int w    = tid >> 6;
    const int lane = tid & 63;
    const int col  = lane & 15;
    const int quad = lane >> 4;
    const int wm   = w >> 1, wn = w & 1;

    #pragma unroll
    for (int i = 0; i < 4; ++i)
        #pragma unroll
        for (int j = 0; j < 4; ++j)
            acc[i][j] = (floatx4){0.f, 0.f, 0.f, 0.f};

    const int o0   = w * 2048 + lane * 16;   // byte offset in 8KB tile
    const int row0 = o0 >> 6;
    const int ke0  = (o0 & 63) >> 1;
    const int loff = (w * 2048) >> 1;        // LDS element offset for this wave

    const ushort* ga = A  + (size_t)(m0 + row0) * GK + ke0;
    const ushort* gb = Bt + (size_t)(n0 + row0) * GK + ke0;

    // prologue: stage k=0 into buffer 0
    #pragma unroll
    for (int t = 0; t < 2; ++t) {
        load_lds16(ga + (size_t)t * 16 * GK, As0 + loff + t * 512);
        load_lds16(gb + (size_t)t * 16 * GK, Bs0 + loff + t * 512);
    }
    __syncthreads();

    for (int k0 = 0; k0 < GK; k0 += 32) {
        const int cur = (k0 >> 5) & 1;
        ushort* Ac = cur ? As1 : As0;
        ushort* Bc = cur ? Bs1 : Bs0;
        ushort* An = cur ? As0 : As1;
        ushort* Bn = cur ? Bs0 : Bs1;

        if (k0 + 32 < GK) {   // issue prefetch BEFORE compute
            #pragma unroll
            for (int t = 0; t < 2; ++t) {
                load_lds16(ga + (k0 + 32) + (size_t)t * 16 * GK, An + loff + t * 512);
                load_lds16(gb + (k0 + 32) + (size_t)t * 16 * GK, Bn + loff + t * 512);
            }
        }

        short8 af[4], bf[4];
        #pragma unroll
        for (int i = 0; i < 4; ++i)
            af[i] = *(const short8*)&Ac[(wm * 64 + i * 16 + col) * 32 + quad * 8];
        #pragma unroll
        for (int j = 0; j < 4; ++j)
            bf[j] = *(const short8*)&Bc[(wn * 64 + j * 16 + col) * 32 + quad * 8];
        #pragma unroll
        for (int i = 0; i < 4; ++i)
            #pragma unroll
            for (int j = 0; j < 4; ++j)
                acc[i][j] = __builtin_amdgcn_mfma_f32_16x16x32_bf16(af[i], bf[j], acc[i][j], 0, 0, 0);

        __syncthreads();   // prefetch landed (covered by the MFMAs above);
                           // also fences cur-buffer reuse two iters later
    }
}

// ---------------------------------------------------------------------------
// 128x64 core (gemm_out only: 512 blocks = 2 blocks/CU vs 1 at 128x128;
// at 1 block/CU there is ZERO inter-block overlap of the barrier drain).
// ---------------------------------------------------------------------------
__device__ __forceinline__ void gemm_core64(
    const ushort* __restrict__ A, const ushort* __restrict__ Bt,
    int m0, int n0, ushort* As0, ushort* As1, ushort* Bs0, ushort* Bs1,
    floatx4 acc[4][2])
{
    const int tid  = threadIdx.x;
    const int w    = tid >> 6;
    const int lane = tid & 63;
    const int col  = lane & 15;
    const int quad = lane >> 4;
    const int wm   = w >> 1, wn = w & 1;

    #pragma unroll
    for (int i = 0; i < 4; ++i)
        #pragma unroll
        for (int j = 0; j < 2; ++j)
            acc[i][j] = (floatx4){0.f, 0.f, 0.f, 0.f};

    const int row0 = w * 16 + (lane >> 2);
    const int ke0  = ((lane & 3) ^ ((lane >> 3) & 3)) * 8;   // ushorts
    const int loff = w * 512;                                // ushort wave base

    const ushort* ga = A  + (size_t)(m0 + row0) * GK + ke0;
    const ushort* gb = Bt + (size_t)(n0 + row0) * GK + ke0;

    load_lds16(ga,               As0 + loff);
    load_lds16(ga + 64 * GK,     As0 + loff + 2048);
    load_lds16(gb,               Bs0 + loff);
    __syncthreads();

    const int sq = (quad ^ ((col >> 1) & 3)) * 8;

    for (int k0 = 0; k0 < GK; k0 += 32) {
        const int cur = (k0 >> 5) & 1;
        ushort* Ac = cur ? As1 : As0;
        ushort* Bc = cur ? Bs1 : Bs0;
        ushort* An = cur ? As0 : As1;
        ushort* Bn = cur ? Bs0 : Bs1;

        if (k0 + 32 < GK) {
            load_lds16(ga + (k0 + 32),           An + loff);
            load_lds16(ga + (k0 + 32) + 64 * GK, An + loff + 2048);
            load_lds16(gb + (k0 + 32),           Bn + loff);
        }

        short8 af[4], bf[2];
        #pragma unroll
        for (int i = 0; i < 4; ++i)
            af[i] = *(const short8*)&Ac[(wm * 64 + i * 16 + col) * 32 + sq];
        #pragma unroll
        for (int j = 0; j < 2; ++j)
            bf[j] = *(const short8*)&Bc[(wn * 32 + j * 16 + col) * 32 + sq];
        #pragma unroll
        for (int i = 0; i < 4; ++i)
            #pragma unroll
            for (int j = 0; j < 2; ++j)
                acc[i][j] = __builtin_amdgcn_mfma_f32_16x16x32_bf16(af[i], bf[j], acc[i][j], 0, 0, 0);

        __syncthreads();
    }
}

// GEMM1: qkv projection; fused split/cast; V emitted transposed. (128x128)
__global__ __launch_bounds__(256) void gemm_qkv_mfma(
    const ushort* __restrict__ A, const ushort* __restrict__ Bt,
    const float* __restrict__ bias,
    ushort* __restrict__ Qb, ushort* __restrict__ Kb, ushort* __restrict__ Vt)
{
    __shared__ __align__(16) ushort As[2][128 * 32];
    __shared__ __align__(16) ushort Bs[2][128 * 32];
    const int n0 = blockIdx.x * 128;
    const int m0 = blockIdx.y * 128;

    floatx4 acc[4][4];
    gemm_core(A, Bt, m0, n0, As[0], As[1], Bs[0], Bs[1], acc);

    const int lane = threadIdx.x & 63;
    const int w    = threadIdx.x >> 6;
    const int col  = lane & 15, quad = lane >> 4;
    const int wm   = w >> 1, wn = w & 1;

    #pragma unroll
    for (int j = 0; j < 4; ++j) {
        const int n = n0 + wn * 64 + j * 16 + col;
        const float bj = bias[n];
        const int part = n >> 10;
        const int h = (n >> 6) & 15;
        const int d = n & 63;
        #pragma unroll
        for (int i = 0; i < 4; ++i)
            #pragma unroll
            for (int r = 0; r < 4; ++r) {
                const int m = m0 + wm * 64 + i * 16 + quad * 4 + r;
                const int b = m >> 11, s = m & 2047;
                const int bh = b * 16 + h;
                const ushort bv = f2bf(acc[i][j][r] + bj);
                if (part == 0)      Qb[((size_t)bh * SEQ + s) * 64 + d] = bv;
                else if (part == 1) Kb[((size_t)bh * SEQ + s) * 64 + d] = bv;
                else                Vt[((size_t)bh * 64 + d) * SEQ + s] = bv;
            }
    }
}

// GEMM2: out = attn_b @ W_out + b_out -> fp32 (128x64 core, 2 blocks/CU)
__global__ __launch_bounds__(256) void gemm_out_mfma(
    const ushort* __restrict__ A, const ushort* __restrict__ Bt,
    const float* __restrict__ bias, float* __restrict__ out)
{
    __shared__ __align__(16) ushort As[2][128 * 32];
    __shared__ __align__(16) ushort Bs[2][64 * 32];
    const int n0 = blockIdx.x * 64;
    const int m0 = blockIdx.y * 128;

    floatx4 acc[4][2];
    gemm_core64(A, Bt, m0, n0, As[0], As[1], Bs[0], Bs[1], acc);

    const int lane = threadIdx.x & 63;
    const int w    = threadIdx.x >> 6;
    const int col  = lane & 15, quad = lane >> 4;
    const int wm   = w >> 1, wn = w & 1;

    #pragma unroll
    for (int j = 0; j < 2; ++j) {
        const int n = n0 + wn * 32 + j * 16 + col;
        const float bj = bias[n];
        #pragma unroll
        for (int i = 0; i < 4; ++i)
            #pragma unroll
            for (int r = 0; r < 4; ++r) {
                const int m = m0 + wm * 64 + i * 16 + quad * 4 + r;
                out[(size_t)m * EMBED_DIM + n] = acc[i][j][r] + bj;
            }
    }
}

// ---------------------------------------------------------------------------
// Flash attention, bf16 MFMA, fragment-ordered async staging, S^T softmax,
// double-buffered K/V with issue-early prefetch (1 barrier per key-tile).
// r7 configuration — best measured (~48us). r8 (no staging) = 2.8x worse;
// r9 (q-tile pairing, 2/CU) = worse; r10 (setprio + Q-direct) = worse
// (setprio regime: barrier-lockstep waves = GEMM m190 null, not m191).
// ---------------------------------------------------------------------------
#define LP 72

__global__ __launch_bounds__(256) void attn_fused(
    const ushort* __restrict__ Qb, const ushort* __restrict__ Kb,
    const ushort* __restrict__ Vt, ushort* __restrict__ out)
{
    const int id = blockIdx.x;
    const int qt = 31 - (id >> 5);          // reversed: long blocks first (LPT)
    const int bh = id & 31;
    const int b  = bh >> 4, h = bh & 15;
    const int q0 = qt * 64;

    __shared__ __align__(16) ushort Qs[8 * 512];        // 8 KB fragment order
    __shared__ __align__(16) ushort Ks[2][8 * 512];     // 16 KB dbuf
    __shared__ __align__(16) ushort Vs[2][8 * 512];     // 16 KB dbuf
    __shared__ __align__(16) ushort Ps[64 * LP];        // 9 KB
    __shared__ __align__(16) float  ls[4][16];

    const int tid  = threadIdx.x;
    const int w    = tid >> 6;
    const int lane = tid & 63;
    const int col  = lane & 15;
    const int quad = lane >> 4;

    // per-lane global staging pointers (fragment-order gather)
    const ushort* kg[2];
    const ushort* vg[2];
    #pragma unroll
    for (int t = 0; t < 2; ++t) {
        kg[t] = Kb + (size_t)bh * SEQ * 64 + (size_t)(w * 16 + col) * 64 + t * 32 + quad * 8;
        vg[t] = Vt + (size_t)bh * 64 * SEQ + (size_t)(w * 16 + col) * SEQ + t * 32 + quad * 8;
    }

    // prologue: stage Q + K/V tile 0 into buffer 0
    {
        const ushort* Qg = Qb + ((size_t)bh * SEQ + q0) * 64;
        #pragma unroll
        for (int t = 0; t < 2; ++t) {
            load_lds16(Qg + (size_t)(w * 16 + col) * 64 + t * 32 + quad * 8,
                       &Qs[(w * 2 + t) * 512]);
            load_lds16(kg[t], &Ks[0][(w * 2 + t) * 512]);
            load_lds16(vg[t], &Vs[0][(w * 2 + t) * 512]);
            kg[t] += 64 * 64;   // -> tile 1
            vg[t] += 64;
        }
    }
    __syncthreads();

    const short8 a0 = *(const short8*)&Qs[(w * 2 + 0) * 512 + lane * 8];
    const short8 a1 = *(const short8*)&Qs[(w * 2 + 1) * 512 + lane * 8];

    floatx4 acc_o[4];
    #pragma unroll
    for (int dbi = 0; dbi < 4; ++dbi) acc_o[dbi] = (floatx4){0.f, 0.f, 0.f, 0.f};
    float l_lane = 0.f;
    const int myq = w * 16 + col;           // tile-local query owned in S^T

    for (int kt = 0; kt <= qt; ++kt) {
        const int cur = kt & 1;
        const ushort* Kc = Ks[cur];
        const ushort* Vc = Vs[cur];

        if (kt < qt) {   // issue-early prefetch of next tile into other buffer
            ushort* Kn = (ushort*)Ks[cur ^ 1];
            ushort* Vn = (ushort*)Vs[cur ^ 1];
            #pragma unroll
            for (int t = 0; t < 2; ++t) {
                load_lds16(kg[t], &Kn[(w * 2 + t) * 512]);
                load_lds16(vg[t], &Vn[(w * 2 + t) * 512]);
                kg[t] += 64 * 64;
                vg[t] += 64;
            }
        }

        // ---- S^T = K Q^T ----
        floatx4 s_acc[4];
        #pragma unroll
        for (int kb = 0; kb < 4; ++kb) {
            short8 k0f = *(const short8*)&Kc[(kb * 2 + 0) * 512 + lane * 8];
            short8 k1f = *(const short8*)&Kc[(kb * 2 + 1) * 512 + lane * 8];
            floatx4 z = (floatx4){0.f, 0.f, 0.f, 0.f};
            z = __builtin_amdgcn_mfma_f32_16x16x32_bf16(k0f, a0, z, 0, 0, 0);
            z = __builtin_amdgcn_mfma_f32_16x16x32_bf16(k1f, a1, z, 0, 0, 0);
            s_acc[kb] = z;   // lane: query col; regs: keys kb*16+quad*4+r
        }

        // ---- p = exp(s/8); write P rows (ds_write_b64 each) ----
        if (kt == qt) {
            #pragma unroll
            for (int kb = 0; kb < 4; ++kb) {
                const int kbase = kb * 16 + quad * 4;
                float p[4];
                #pragma unroll
                for (int r = 0; r < 4; ++r) {
                    float e = __expf(s_acc[kb][r] * 0.125f);
                    p[r] = (kbase + r > myq) ? 0.f : e;
                    l_lane += p[r];
                }
                uint2 u = { bfpack2(p[0], p[1]), bfpack2(p[2], p[3]) };
                *(uint2*)&Ps[myq * LP + kbase] = u;
            }
        } else {
            #pragma unroll
            for (int kb = 0; kb < 4; ++kb) {
                const int kbase = kb * 16 + quad * 4;
                float p[4];
                #pragma unroll
                for (int r = 0; r < 4; ++r) {
                    p[r] = __expf(s_acc[kb][r] * 0.125f);
                    l_lane += p[r];
                }
                uint2 u = { bfpack2(p[0], p[1]), bfpack2(p[2], p[3]) };
                *(uint2*)&Ps[myq * LP + kbase] = u;
            }
        }

        // ---- O += P V  (Ps rows wave-private) ----
        short8 pa0 = *(const short8*)&Ps[(w * 16 + col) * LP + quad * 8];
        short8 pa1 = *(const short8*)&Ps[(w * 16 + col) * LP + 32 + quad * 8];
        #pragma unroll
        for (int dbi = 0; dbi < 4; ++dbi) {
            short8 vb0 = *(const short8*)&Vc[(dbi * 2 + 0) * 512 + lane * 8];
            short8 vb1 = *(const short8*)&Vc[(dbi * 2 + 1) * 512 + lane * 8];
            acc_o[dbi] = __builtin_amdgcn_mfma_f32_16x16x32_bf16(pa0, vb0, acc_o[dbi], 0, 0, 0);
            acc_o[dbi] = __builtin_amdgcn_mfma_f32_16x16x32_bf16(pa1, vb1, acc_o[dbi], 0, 0, 0);
        }

        __syncthreads();   // prefetch landed (covered by compute above);
                           // fences cur-buffer overwrite two iters later
    }

    // ---- finalize l ----
    l_lane += __shfl_xor(l_lane, 16);
    l_lane += __shfl_xor(l_lane, 32);
    if (quad == 0) ls[w][col] = 1.f / l_lane;   // wave-private
    float4 invv = *(const float4*)&ls[w][quad * 4];

    #pragma unroll
    for (int dbi = 0; dbi < 4; ++dbi)
        #pragma unroll
        for (int r = 0; r < 4; ++r) {
            int q = q0 + w * 16 + quad * 4 + r;
            int d = dbi * 16 + col;
            float inv = (r == 0) ? invv.x : (r == 1) ? invv.y : (r == 2) ? invv.z : invv.w;
            out[((size_t)(b * SEQ + q)) * EMBED_DIM + h * 64 + d] = f2bf(acc_o[dbi][r] * inv);
        }
}

// ---------------------------------------------------------------------------
extern "C" void kernel_launch(void* const* d_in, const int* in_sizes, int n_in,
                              void* d_out, int out_size, void* d_ws, size_t ws_size,
                              hipStream_t stream)
{
    const float* x     = (const float*)d_in[0];
    const float* W_qkv = (const float*)d_in[1];
    const float* b_qkv = (const float*)d_in[2];
    const float* W_out = (const float*)d_in[3];
    const float* b_out = (const float*)d_in[4];
    float* out = (float*)d_out;

    const int M  = BATCH * SEQ;            // 4096
    const int D  = EMBED_DIM;              // 1024
    const int N1 = 3 * D;                  // 3072
    const size_t HE = (size_t)BATCH * NUM_HEADS * SEQ * 64;  // 4M

    ushort* xb    = (ushort*)d_ws;
    ushort* Wqb_t = xb + (size_t)M * D;
    ushort* Wob_t = Wqb_t + (size_t)D * N1;
    ushort* Qb    = Wob_t + (size_t)D * D;
    ushort* Kb    = Qb + HE;
    ushort* Vt    = Kb + HE;
    ushort* attnb = Vt + HE;

    // 0) fused prep: cast x, transpose+cast weights
    prep_all<<<5120, 256, 0, stream>>>(x, W_qkv, W_out, xb, Wqb_t, Wob_t);

    // 1) qkv projection — 128x128 (round-0 best), 768 blocks = 3/CU
    gemm_qkv_mfma<<<dim3(N1 / 128, M / 128), 256, 0, stream>>>(
        xb, Wqb_t, b_qkv, Qb, Kb, Vt);

    // 2) flash attention — staged v1 (r7 best), 1024 blocks = 3/CU
    attn_fused<<<dim3(32 * 32), 256, 0, stream>>>(Qb, Kb, Vt, attnb);

    // 3) output projection — 128x64, 512 blocks = 2/CU
    gemm_out_mfma<<<dim3(D / 64, M / 128), 256, 0, stream>>>(
        attnb, Wob_t, b_out, out);
}

// Round 12
// 184.292 us; speedup vs baseline: 1.5010x; 1.0240x over previous
//
#include <hip/hip_runtime.h>
#include <hip/hip_bf16.h>
#include <math.h>

#define EMBED_DIM 1024
#define NUM_HEADS 16
#define HEAD_DIM 64
#define BATCH 2
#define SEQ 2048

using short8  = __attribute__((ext_vector_type(8))) short;
using floatx4 = __attribute__((ext_vector_type(4))) float;

__device__ __forceinline__ ushort f2bf(float f) {
    unsigned u = __float_as_uint(f);
    u = (u + 0x7FFFu + ((u >> 16) & 1u)) >> 16;   // RNE
    return (ushort)u;
}

// pack two floats to bf16x2 (half-up rounding — P values are in [0,1], fine)
__device__ __forceinline__ unsigned bfpack2(float a, float b) {
    return ((__float_as_uint(a) + 0x8000u) >> 16) |
           (((__float_as_uint(b) + 0x8000u) >> 16) << 16);
}

// async global->LDS, 16B per lane; LDS dest = wave-uniform base + lane*16.
__device__ __forceinline__ void load_lds16(const ushort* g, ushort* l) {
    __builtin_amdgcn_global_load_lds(
        (const __attribute__((address_space(1))) void*)g,
        (__attribute__((address_space(3))) void*)l, 16, 0, 0);
}

// ---------------------------------------------------------------------------
// Fused prep: cast x -> bf16, transpose+cast W_qkv and W_out.
// ---------------------------------------------------------------------------
__device__ __forceinline__ void tc_tile(
    const float* __restrict__ W, ushort* __restrict__ Wt,
    int K, int N, int n0, int k0, float (*t)[65])
{
    const int c = threadIdx.x & 63, r0 = (threadIdx.x >> 6) * 16;
    #pragma unroll
    for (int r = 0; r < 16; ++r)
        t[r0 + r][c] = W[(size_t)(k0 + r0 + r) * N + n0 + c];
    __syncthreads();
    #pragma unroll
    for (int r = 0; r < 16; ++r)
        Wt[(size_t)(n0 + r0 + r) * K + k0 + c] = f2bf(t[c][r0 + r]);
}

__global__ __launch_bounds__(256) void prep_all(
    const float* __restrict__ x, const float* __restrict__ W_qkv,
    const float* __restrict__ W_out,
    ushort* __restrict__ xb, ushort* __restrict__ Wqb_t, ushort* __restrict__ Wob_t)
{
    __shared__ float t[64][65];
    const int bx = blockIdx.x;
    if (bx < 4096) {
        int i = (bx * 256 + threadIdx.x) * 4;
        float4 v = *(const float4*)&x[i];
        ushort4 o = { f2bf(v.x), f2bf(v.y), f2bf(v.z), f2bf(v.w) };
        *(ushort4*)&xb[i] = o;
    } else if (bx < 4096 + 768) {
        int b = bx - 4096;
        tc_tile(W_qkv, Wqb_t, 1024, 3072, (b % 48) * 64, (b / 48) * 64, t);
    } else {
        int b = bx - 4864;
        tc_tile(W_out, Wob_t, 1024, 1024, (b % 16) * 64, (b / 16) * 64, t);
    }
}

// ---------------------------------------------------------------------------
// bf16 MFMA GEMM core, 128x128, double-buffered — round-0 best (46.5us).
// Measured local optimum (rounds 1-6). Parked; used by gemm_qkv only.
// ---------------------------------------------------------------------------
#define GK 1024

__device__ __forceinline__ void gemm_core(
    const ushort* __restrict__ A, const ushort* __restrict__ Bt,
    int m0, int n0, ushort* As0, ushort* As1, ushort* Bs0, ushort* Bs1,
    floatx4 acc[4][4])
{
    const int tid  = threadIdx.x;
    const int w    = tid >> 6;
    const int lane = tid & 63;
    const int col  = lane & 15;
    const int quad = lane >> 4;
    const int wm   = w >> 1, wn = w & 1;

    #pragma unroll
    for (int i = 0; i < 4; ++i)
        #pragma unroll
        for (int j = 0; j < 4; ++j)
            acc[i][j] = (floatx4){0.f, 0.f, 0.f, 0.f};

    const int o0   = w * 2048 + lane * 16;   // byte offset in 8KB tile
    const int row0 = o0 >> 6;
    const int ke0  = (o0 & 63) >> 1;
    const int loff = (w * 2048) >> 1;        // LDS element offset for this wave

    const ushort* ga = A  + (size_t)(m0 + row0) * GK + ke0;
    const ushort* gb = Bt + (size_t)(n0 + row0) * GK + ke0;

    // prologue: stage k=0 into buffer 0
    #pragma unroll
    for (int t = 0; t < 2; ++t) {
        load_lds16(ga + (size_t)t * 16 * GK, As0 + loff + t * 512);
        load_lds16(gb + (size_t)t * 16 * GK, Bs0 + loff + t * 512);
    }
    __syncthreads();

    for (int k0 = 0; k0 < GK; k0 += 32) {
        const int cur = (k0 >> 5) & 1;
        ushort* Ac = cur ? As1 : As0;
        ushort* Bc = cur ? Bs1 : Bs0;
        ushort* An = cur ? As0 : As1;
        ushort* Bn = cur ? Bs0 : Bs1;

        if (k0 + 32 < GK) {   // issue prefetch BEFORE compute
            #pragma unroll
            for (int t = 0; t < 2; ++t) {
                load_lds16(ga + (k0 + 32) + (size_t)t * 16 * GK, An + loff + t * 512);
                load_lds16(gb + (k0 + 32) + (size_t)t * 16 * GK, Bn + loff + t * 512);
            }
        }

        short8 af[4], bf[4];
        #pragma unroll
        for (int i = 0; i < 4; ++i)
            af[i] = *(const short8*)&Ac[(wm * 64 + i * 16 + col) * 32 + quad * 8];
        #pragma unroll
        for (int j = 0; j < 4; ++j)
            bf[j] = *(const short8*)&Bc[(wn * 64 + j * 16 + col) * 32 + quad * 8];
        #pragma unroll
        for (int i = 0; i < 4; ++i)
            #pragma unroll
            for (int j = 0; j < 4; ++j)
                acc[i][j] = __builtin_amdgcn_mfma_f32_16x16x32_bf16(af[i], bf[j], acc[i][j], 0, 0, 0);

        __syncthreads();   // prefetch landed (covered by the MFMAs above);
                           // also fences cur-buffer reuse two iters later
    }
}

// ---------------------------------------------------------------------------
// 128x64 core, BK=64 (round 12; gemm_out only). gemm_out is grid-limited at
// 2 blocks/CU, so the dominant cost is the per-K-step DMA-drain+barrier with
// weak TLP cover. BK=64 halves the step count 32->16 at UNCHANGED occupancy
// (LDS 48KB still allows 3/CU; grid gives 2). Same total loads/MFMAs.
//   LDS tiles: A[128][64] (16KB) x2 dbuf, B[64][64] (8KB) x2 dbuf = 48KB.
//   Swizzle (128B rows): linear 16B-chunk c of row r holds logical
//   c ^ (r&7); stage source chunk (l&7)^(l>>3) (each 8-lane group reads one
//   permuted 128B row -> coalescing kept); reads use ((kk*4+quad)^(col&7)).
//   -> 8 distinct bank-groups x 2 lanes = 2-way = free (m136).
// ---------------------------------------------------------------------------
__device__ __forceinline__ void gemm_core64(
    const ushort* __restrict__ A, const ushort* __restrict__ Bt,
    int m0, int n0, ushort* As0, ushort* As1, ushort* Bs0, ushort* Bs1,
    floatx4 acc[4][2])
{
    const int tid  = threadIdx.x;
    const int w    = tid >> 6;
    const int lane = tid & 63;
    const int col  = lane & 15;
    const int quad = lane >> 4;
    const int wm   = w >> 1, wn = w & 1;

    #pragma unroll
    for (int i = 0; i < 4; ++i)
        #pragma unroll
        for (int j = 0; j < 2; ++j)
            acc[i][j] = (floatx4){0.f, 0.f, 0.f, 0.f};

    // staging: pass = 4KB = 32 rows of 128B; lane -> row w*8+(l>>3), chunk l&7
    const int srow = w * 8 + (lane >> 3);
    const int sc   = ((lane & 7) ^ (lane >> 3)) * 8;   // swizzled source chunk
    const int loff = w * 512;                          // ushort wave base / pass

    const ushort* ga = A  + (size_t)(m0 + srow) * GK + sc;
    const ushort* gb = Bt + (size_t)(n0 + srow) * GK + sc;

    // prologue: stage k=0 into buffer 0 (A: 4 passes, B: 2 passes)
    #pragma unroll
    for (int p = 0; p < 4; ++p)
        load_lds16(ga + (size_t)p * 32 * GK, As0 + p * 2048 + loff);
    #pragma unroll
    for (int p = 0; p < 2; ++p)
        load_lds16(gb + (size_t)p * 32 * GK, Bs0 + p * 2048 + loff);
    __syncthreads();

    // swizzled read chunks for kk=0,1 (row&7 == col&7 for all fragment rows)
    const int c7  = col & 7;
    const int rq0 = (quad ^ c7) * 8;
    const int rq1 = ((4 + quad) ^ c7) * 8;

    for (int k0 = 0; k0 < GK; k0 += 64) {
        const int cur = (k0 >> 6) & 1;
        ushort* Ac = cur ? As1 : As0;
        ushort* Bc = cur ? Bs1 : Bs0;
        ushort* An = cur ? As0 : As1;
        ushort* Bn = cur ? Bs0 : Bs1;

        if (k0 + 64 < GK) {   // issue prefetch BEFORE compute
            #pragma unroll
            for (int p = 0; p < 4; ++p)
                load_lds16(ga + (k0 + 64) + (size_t)p * 32 * GK, An + p * 2048 + loff);
            #pragma unroll
            for (int p = 0; p < 2; ++p)
                load_lds16(gb + (k0 + 64) + (size_t)p * 32 * GK, Bn + p * 2048 + loff);
        }

        short8 af[4][2], bf[2][2];
        #pragma unroll
        for (int i = 0; i < 4; ++i) {
            const int r = (wm * 64 + i * 16 + col) * 64;
            af[i][0] = *(const short8*)&Ac[r + rq0];
            af[i][1] = *(const short8*)&Ac[r + rq1];
        }
        #pragma unroll
        for (int j = 0; j < 2; ++j) {
            const int r = (wn * 32 + j * 16 + col) * 64;
            bf[j][0] = *(const short8*)&Bc[r + rq0];
            bf[j][1] = *(const short8*)&Bc[r + rq1];
        }
        #pragma unroll
        for (int i = 0; i < 4; ++i)
            #pragma unroll
            for (int j = 0; j < 2; ++j) {
                acc[i][j] = __builtin_amdgcn_mfma_f32_16x16x32_bf16(af[i][0], bf[j][0], acc[i][j], 0, 0, 0);
                acc[i][j] = __builtin_amdgcn_mfma_f32_16x16x32_bf16(af[i][1], bf[j][1], acc[i][j], 0, 0, 0);
            }

        __syncthreads();   // prefetch landed (covered by MFMAs + other block);
                           // fences cur-buffer reuse two iters later
    }
}

// GEMM1: qkv projection; fused split/cast; V emitted transposed. (128x128)
__global__ __launch_bounds__(256) void gemm_qkv_mfma(
    const ushort* __restrict__ A, const ushort* __restrict__ Bt,
    const float* __restrict__ bias,
    ushort* __restrict__ Qb, ushort* __restrict__ Kb, ushort* __restrict__ Vt)
{
    __shared__ __align__(16) ushort As[2][128 * 32];
    __shared__ __align__(16) ushort Bs[2][128 * 32];
    const int n0 = blockIdx.x * 128;
    const int m0 = blockIdx.y * 128;

    floatx4 acc[4][4];
    gemm_core(A, Bt, m0, n0, As[0], As[1], Bs[0], Bs[1], acc);

    const int lane = threadIdx.x & 63;
    const int w    = threadIdx.x >> 6;
    const int col  = lane & 15, quad = lane >> 4;
    const int wm   = w >> 1, wn = w & 1;

    #pragma unroll
    for (int j = 0; j < 4; ++j) {
        const int n = n0 + wn * 64 + j * 16 + col;
        const float bj = bias[n];
        const int part = n >> 10;
        const int h = (n >> 6) & 15;
        const int d = n & 63;
        #pragma unroll
        for (int i = 0; i < 4; ++i)
            #pragma unroll
            for (int r = 0; r < 4; ++r) {
                const int m = m0 + wm * 64 + i * 16 + quad * 4 + r;
                const int b = m >> 11, s = m & 2047;
                const int bh = b * 16 + h;
                const ushort bv = f2bf(acc[i][j][r] + bj);
                if (part == 0)      Qb[((size_t)bh * SEQ + s) * 64 + d] = bv;
                else if (part == 1) Kb[((size_t)bh * SEQ + s) * 64 + d] = bv;
                else                Vt[((size_t)bh * 64 + d) * SEQ + s] = bv;
            }
    }
}

// GEMM2: out = attn_b @ W_out + b_out -> fp32 (128x64 core, BK=64, 2/CU)
__global__ __launch_bounds__(256) void gemm_out_mfma(
    const ushort* __restrict__ A, const ushort* __restrict__ Bt,
    const float* __restrict__ bias, float* __restrict__ out)
{
    __shared__ __align__(16) ushort As[2][128 * 64];   // 32 KB
    __shared__ __align__(16) ushort Bs[2][64 * 64];    // 16 KB
    const int n0 = blockIdx.x * 64;
    const int m0 = blockIdx.y * 128;

    floatx4 acc[4][2];
    gemm_core64(A, Bt, m0, n0, As[0], As[1], Bs[0], Bs[1], acc);

    const int lane = threadIdx.x & 63;
    const int w    = threadIdx.x >> 6;
    const int col  = lane & 15, quad = lane >> 4;
    const int wm   = w >> 1, wn = w & 1;

    #pragma unroll
    for (int j = 0; j < 2; ++j) {
        const int n = n0 + wn * 32 + j * 16 + col;
        const float bj = bias[n];
        #pragma unroll
        for (int i = 0; i < 4; ++i)
            #pragma unroll
            for (int r = 0; r < 4; ++r) {
                const int m = m0 + wm * 64 + i * 16 + quad * 4 + r;
                out[(size_t)m * EMBED_DIM + n] = acc[i][j][r] + bj;
            }
    }
}

// ---------------------------------------------------------------------------
// Flash attention — r7 configuration, best measured (~47us). Untouched.
// ---------------------------------------------------------------------------
#define LP 72

__global__ __launch_bounds__(256) void attn_fused(
    const ushort* __restrict__ Qb, const ushort* __restrict__ Kb,
    const ushort* __restrict__ Vt, ushort* __restrict__ out)
{
    const int id = blockIdx.x;
    const int qt = 31 - (id >> 5);          // reversed: long blocks first (LPT)
    const int bh = id & 31;
    const int b  = bh >> 4, h = bh & 15;
    const int q0 = qt * 64;

    __shared__ __align__(16) ushort Qs[8 * 512];        // 8 KB fragment order
    __shared__ __align__(16) ushort Ks[2][8 * 512];     // 16 KB dbuf
    __shared__ __align__(16) ushort Vs[2][8 * 512];     // 16 KB dbuf
    __shared__ __align__(16) ushort Ps[64 * LP];        // 9 KB
    __shared__ __align__(16) float  ls[4][16];

    const int tid  = threadIdx.x;
    const int w    = tid >> 6;
    const int lane = tid & 63;
    const int col  = lane & 15;
    const int quad = lane >> 4;

    // per-lane global staging pointers (fragment-order gather)
    const ushort* kg[2];
    const ushort* vg[2];
    #pragma unroll
    for (int t = 0; t < 2; ++t) {
        kg[t] = Kb + (size_t)bh * SEQ * 64 + (size_t)(w * 16 + col) * 64 + t * 32 + quad * 8;
        vg[t] = Vt + (size_t)bh * 64 * SEQ + (size_t)(w * 16 + col) * SEQ + t * 32 + quad * 8;
    }

    // prologue: stage Q + K/V tile 0 into buffer 0
    {
        const ushort* Qg = Qb + ((size_t)bh * SEQ + q0) * 64;
        #pragma unroll
        for (int t = 0; t < 2; ++t) {
            load_lds16(Qg + (size_t)(w * 16 + col) * 64 + t * 32 + quad * 8,
                       &Qs[(w * 2 + t) * 512]);
            load_lds16(kg[t], &Ks[0][(w * 2 + t) * 512]);
            load_lds16(vg[t], &Vs[0][(w * 2 + t) * 512]);
            kg[t] += 64 * 64;   // -> tile 1
            vg[t] += 64;
        }
    }
    __syncthreads();

    const short8 a0 = *(const short8*)&Qs[(w * 2 + 0) * 512 + lane * 8];
    const short8 a1 = *(const short8*)&Qs[(w * 2 + 1) * 512 + lane * 8];

    floatx4 acc_o[4];
    #pragma unroll
    for (int dbi = 0; dbi < 4; ++dbi) acc_o[dbi] = (floatx4){0.f, 0.f, 0.f, 0.f};
    float l_lane = 0.f;
    const int myq = w * 16 + col;           // tile-local query owned in S^T

    for (int kt = 0; kt <= qt; ++kt) {
        const int cur = kt & 1;
        const ushort* Kc = Ks[cur];
        const ushort* Vc = Vs[cur];

        if (kt < qt) {   // issue-early prefetch of next tile into other buffer
            ushort* Kn = (ushort*)Ks[cur ^ 1];
            ushort* Vn = (ushort*)Vs[cur ^ 1];
            #pragma unroll
            for (int t = 0; t < 2; ++t) {
                load_lds16(kg[t], &Kn[(w * 2 + t) * 512]);
                load_lds16(vg[t], &Vn[(w * 2 + t) * 512]);
                kg[t] += 64 * 64;
                vg[t] += 64;
            }
        }

        // ---- S^T = K Q^T ----
        floatx4 s_acc[4];
        #pragma unroll
        for (int kb = 0; kb < 4; ++kb) {
            short8 k0f = *(const short8*)&Kc[(kb * 2 + 0) * 512 + lane * 8];
            short8 k1f = *(const short8*)&Kc[(kb * 2 + 1) * 512 + lane * 8];
            floatx4 z = (floatx4){0.f, 0.f, 0.f, 0.f};
            z = __builtin_amdgcn_mfma_f32_16x16x32_bf16(k0f, a0, z, 0, 0, 0);
            z = __builtin_amdgcn_mfma_f32_16x16x32_bf16(k1f, a1, z, 0, 0, 0);
            s_acc[kb] = z;   // lane: query col; regs: keys kb*16+quad*4+r
        }

        // ---- p = exp(s/8); write P rows (ds_write_b64 each) ----
        if (kt == qt) {
            #pragma unroll
            for (int kb = 0; kb < 4; ++kb) {
                const int kbase = kb * 16 + quad * 4;
                float p[4];
                #pragma unroll
                for (int r = 0; r < 4; ++r) {
                    float e = __expf(s_acc[kb][r] * 0.125f);
                    p[r] = (kbase + r > myq) ? 0.f : e;
                    l_lane += p[r];
                }
                uint2 u = { bfpack2(p[0], p[1]), bfpack2(p[2], p[3]) };
                *(uint2*)&Ps[myq * LP + kbase] = u;
            }
        } else {
            #pragma unroll
            for (int kb = 0; kb < 4; ++kb) {
                const int kbase = kb * 16 + quad * 4;
                float p[4];
                #pragma unroll
                for (int r = 0; r < 4; ++r) {
                    p[r] = __expf(s_acc[kb][r] * 0.125f);
                    l_lane += p[r];
                }
                uint2 u = { bfpack2(p[0], p[1]), bfpack2(p[2], p[3]) };
                *(uint2*)&Ps[myq * LP + kbase] = u;
            }
        }

        // ---- O += P V  (Ps rows wave-private) ----
        short8 pa0 = *(const short8*)&Ps[(w * 16 + col) * LP + quad * 8];
        short8 pa1 = *(const short8*)&Ps[(w * 16 + col) * LP + 32 + quad * 8];
        #pragma unroll
        for (int dbi = 0; dbi < 4; ++dbi) {
            short8 vb0 = *(const short8*)&Vc[(dbi * 2 + 0) * 512 + lane * 8];
            short8 vb1 = *(const short8*)&Vc[(dbi * 2 + 1) * 512 + lane * 8];
            acc_o[dbi] = __builtin_amdgcn_mfma_f32_16x16x32_bf16(pa0, vb0, acc_o[dbi], 0, 0, 0);
            acc_o[dbi] = __builtin_amdgcn_mfma_f32_16x16x32_bf16(pa1, vb1, acc_o[dbi], 0, 0, 0);
        }

        __syncthreads();   // prefetch landed (covered by compute above);
                           // fences cur-buffer overwrite two iters later
    }

    // ---- finalize l ----
    l_lane += __shfl_xor(l_lane, 16);
    l_lane += __shfl_xor(l_lane, 32);
    if (quad == 0) ls[w][col] = 1.f / l_lane;   // wave-private
    float4 invv = *(const float4*)&ls[w][quad * 4];

    #pragma unroll
    for (int dbi = 0; dbi < 4; ++dbi)
        #pragma unroll
        for (int r = 0; r < 4; ++r) {
            int q = q0 + w * 16 + quad * 4 + r;
            int d = dbi * 16 + col;
            float inv = (r == 0) ? invv.x : (r == 1) ? invv.y : (r == 2) ? invv.z : invv.w;
            out[((size_t)(b * SEQ + q)) * EMBED_DIM + h * 64 + d] = f2bf(acc_o[dbi][r] * inv);
        }
}

// ---------------------------------------------------------------------------
extern "C" void kernel_launch(void* const* d_in, const int* in_sizes, int n_in,
                              void* d_out, int out_size, void* d_ws, size_t ws_size,
                              hipStream_t stream)
{
    const float* x     = (const float*)d_in[0];
    const float* W_qkv = (const float*)d_in[1];
    const float* b_qkv = (const float*)d_in[2];
    const float* W_out = (const float*)d_in[3];
    const float* b_out = (const float*)d_in[4];
    float* out = (float*)d_out;

    const int M  = BATCH * SEQ;            // 4096
    const int D  = EMBED_DIM;              // 1024
    const int N1 = 3 * D;                  // 3072
    const size_t HE = (size_t)BATCH * NUM_HEADS * SEQ * 64;  // 4M

    ushort* xb    = (ushort*)d_ws;
    ushort* Wqb_t = xb + (size_t)M * D;
    ushort* Wob_t = Wqb_t + (size_t)D * N1;
    ushort* Qb    = Wob_t + (size_t)D * D;
    ushort* Kb    = Qb + HE;
    ushort* Vt    = Kb + HE;
    ushort* attnb = Vt + HE;

    // 0) fused prep: cast x, transpose+cast weights
    prep_all<<<5120, 256, 0, stream>>>(x, W_qkv, W_out, xb, Wqb_t, Wob_t);

    // 1) qkv projection — 128x128 (round-0 best), 768 blocks = 3/CU
    gemm_qkv_mfma<<<dim3(N1 / 128, M / 128), 256, 0, stream>>>(
        xb, Wqb_t, b_qkv, Qb, Kb, Vt);

    // 2) flash attention — staged v1 (r7 best), 1024 blocks = 3/CU
    attn_fused<<<dim3(32 * 32), 256, 0, stream>>>(Qb, Kb, Vt, attnb);

    // 3) output projection — 128x64, BK=64 (16 K-steps), 512 blocks = 2/CU
    gemm_out_mfma<<<dim3(D / 64, M / 128), 256, 0, stream>>>(
        attnb, Wob_t, b_out, out);
}